// Round 1
// baseline (5172.811 us; speedup 1.0000x reference)
//
#include <hip/hip_runtime.h>
#include <hip/hip_bf16.h>
#include <math.h>

// B=8 T=2048 E=512 H=8 | NQ_H=4 NL=2 | NQ_F=8 FFN=2048
// Closed form: qout_q = cos(x_q)*A_q - sin(x_q)*B_q with A=<S|Z|S>, B=<S|X|S>,
// S = state after the parameterized layers (data-independent). Verified:
// RY(t)^dag Z RY(t) = cos t Z - sin t X; other-wire RYs commute with Z_q.

#define B_   8
#define T_   2048
#define E_   512
#define BT_  (B_*T_)

// ---------------------------------------------------------------- K0: setup
__global__ void k0_setup(const float* __restrict__ hp, const float* __restrict__ fp,
                         const float* __restrict__ wo, float* __restrict__ cAB,
                         float* __restrict__ wo32) {
  __shared__ float fst[256];
  int t = threadIdx.x;
  if (t < 8) {                       // per-head 4-qubit circuits (16 amps)
    float st[16];
    #pragma unroll
    for (int i=0;i<16;i++) st[i]=0.f;
    st[0]=1.f;
    for (int l=0;l<2;l++){
      for (int q=0;q<4;q++){
        float th = 0.5f*hp[t*8 + l*4 + q];
        float c = cosf(th), s = sinf(th);
        int str = 1<<(3-q);
        for (int i=0;i<16;i++) if (!(i & str)) {
          float s0=st[i], s1=st[i|str];
          st[i]     = c*s0 - s*s1;
          st[i|str] = s*s0 + c*s1;
        }
      }
      for (int q=0;q<4;q++){         // CNOT chain + ring
        int ctrl = (q<3)? q : 3, tgt = (q<3)? q+1 : 0;
        int cs = 1<<(3-ctrl), tsr = 1<<(3-tgt);
        for (int i=0;i<16;i++) if ((i&cs) && !(i&tsr)) {
          float tmp = st[i]; st[i]=st[i|tsr]; st[i|tsr]=tmp;
        }
      }
    }
    for (int q=0;q<4;q++){
      int str = 1<<(3-q);
      float A=0.f, Bv=0.f;
      for (int i=0;i<16;i++){
        A  += st[i]*st[i] * ((i&str)? -1.f : 1.f);
        Bv += st[i]*st[i^str];
      }
      cAB[t*4+q]    = A;             // headA[h][q]
      cAB[32+t*4+q] = Bv;            // headB[h][q]
    }
  }
  if (t == 8) {                      // FFN 8-qubit circuit (256 amps), L=1, row 0
    for (int i=0;i<256;i++) fst[i]=0.f;
    fst[0]=1.f;
    for (int q=0;q<8;q++){
      float th = 0.5f*fp[q];
      float c = cosf(th), s = sinf(th);
      int str = 1<<(7-q);
      for (int i=0;i<256;i++) if (!(i & str)) {
        float s0=fst[i], s1=fst[i|str];
        fst[i]     = c*s0 - s*s1;
        fst[i|str] = s*s0 + c*s1;
      }
    }
    for (int q=0;q<8;q++){
      int ctrl = (q<7)? q : 7, tgt = (q<7)? q+1 : 0;
      int cs = 1<<(7-ctrl), tsr = 1<<(7-tgt);
      for (int i=0;i<256;i++) if ((i&cs) && !(i&tsr)) {
        float tmp = fst[i]; fst[i]=fst[i|tsr]; fst[i|tsr]=tmp;
      }
    }
    for (int q=0;q<8;q++){
      int str = 1<<(7-q);
      float A=0.f, Bv=0.f;
      for (int i=0;i<256;i++){
        A  += fst[i]*fst[i] * ((i&str)? -1.f : 1.f);
        Bv += fst[i]*fst[i^str];
      }
      cAB[64+q] = A;                 // ffnA
      cAB[72+q] = Bv;                // ffnB
    }
  }
  // pack the 32 used columns of wo: wo32[e][c] = wo[e][(c/4)*64 + (c%4)]
  for (int idx = t; idx < 512*32; idx += 64){
    int e = idx >> 5, c = idx & 31;
    wo32[idx] = wo[(size_t)e*512 + (c>>2)*64 + (c&3)];
  }
}

// -------------------------------------------------- K1: q,k = x @ {wq,wk}^T
__global__ __launch_bounds__(256) void k1_qk(const float* __restrict__ x,
    const float* __restrict__ wq, const float* __restrict__ wk,
    float* __restrict__ qb, float* __restrict__ kb) {
  const float* w  = (blockIdx.z == 0) ? wq : wk;
  float*       ob = (blockIdx.z == 0) ? qb : kb;
  int n0 = blockIdx.x * 64, m0 = blockIdx.y * 64;
  __shared__ float Xs[64][36];
  __shared__ float Ws[64][36];
  int t = threadIdx.x, ty = t >> 4, tx = t & 15;
  float acc[4][4] = {};
  for (int k0 = 0; k0 < 512; k0 += 32) {
    #pragma unroll
    for (int u=0; u<2; u++){
      int idx = t + u*256;
      int r = idx >> 3, c4 = (idx & 7) * 4;
      *(float4*)&Xs[r][c4] = *(const float4*)(x + (size_t)(m0+r)*512 + k0 + c4);
      *(float4*)&Ws[r][c4] = *(const float4*)(w + (size_t)(n0+r)*512 + k0 + c4);
    }
    __syncthreads();
    #pragma unroll
    for (int kk=0; kk<32; kk++){
      float a0=Xs[ty*4+0][kk], a1=Xs[ty*4+1][kk], a2=Xs[ty*4+2][kk], a3=Xs[ty*4+3][kk];
      float b0=Ws[tx*4+0][kk], b1=Ws[tx*4+1][kk], b2=Ws[tx*4+2][kk], b3=Ws[tx*4+3][kk];
      acc[0][0]+=a0*b0; acc[0][1]+=a0*b1; acc[0][2]+=a0*b2; acc[0][3]+=a0*b3;
      acc[1][0]+=a1*b0; acc[1][1]+=a1*b1; acc[1][2]+=a1*b2; acc[1][3]+=a1*b3;
      acc[2][0]+=a2*b0; acc[2][1]+=a2*b1; acc[2][2]+=a2*b2; acc[2][3]+=a2*b3;
      acc[3][0]+=a3*b0; acc[3][1]+=a3*b1; acc[3][2]+=a3*b2; acc[3][3]+=a3*b3;
    }
    __syncthreads();
  }
  #pragma unroll
  for (int i=0;i<4;i++){
    float4 v = make_float4(acc[i][0], acc[i][1], acc[i][2], acc[i][3]);
    *(float4*)(ob + (size_t)(m0+ty*4+i)*512 + n0 + tx*4) = v;
  }
}

// ------------------------------------- K1v: v32 = x @ wv[used_rows]^T (32 cols)
__global__ __launch_bounds__(256) void k1_v32(const float* __restrict__ x,
    const float* __restrict__ wv, float* __restrict__ v32) {
  int m0 = blockIdx.x * 64;
  __shared__ float Xs[64][36];
  __shared__ float Ws[32][36];
  int t = threadIdx.x;
  int m = t >> 2, c0 = (t & 3) * 8;
  float acc[8] = {};
  for (int k0 = 0; k0 < 512; k0 += 32) {
    #pragma unroll
    for (int u=0; u<2; u++){
      int idx = t + u*256;
      int r = idx >> 3, c4 = (idx & 7) * 4;
      *(float4*)&Xs[r][c4] = *(const float4*)(x + (size_t)(m0+r)*512 + k0 + c4);
    }
    { int r = t >> 3, c4 = (t & 7) * 4;      // 32x32 = 256 float4
      int wrow = (r>>2)*64 + (r&3);
      *(float4*)&Ws[r][c4] = *(const float4*)(wv + (size_t)wrow*512 + k0 + c4);
    }
    __syncthreads();
    #pragma unroll
    for (int kk=0; kk<32; kk++){
      float xv = Xs[m][kk];
      #pragma unroll
      for (int j=0;j<8;j++) acc[j] += xv * Ws[c0+j][kk];
    }
    __syncthreads();
  }
  #pragma unroll
  for (int j=0;j<8;j+=4){
    float4 v = make_float4(acc[j], acc[j+1], acc[j+2], acc[j+3]);
    *(float4*)(v32 + (size_t)(m0+m)*32 + c0 + j) = v;
  }
}

// ---------------------------- K2: flash attention (d=512) + circuit trig epilogue
__global__ __launch_bounds__(256) void k2_attn(const float* __restrict__ q,
    const float* __restrict__ k, const float* __restrict__ v32,
    const float* __restrict__ cAB, float* __restrict__ q32out) {
  int b = blockIdx.y, m0 = blockIdx.x * 64;
  const float* qbp = q   + (size_t)b*T_*512;
  const float* kbp = k   + (size_t)b*T_*512;
  const float* vbp = v32 + (size_t)b*T_*32;
  __shared__ float Qs[64][36], Ks[64][36];
  __shared__ float Ss[64][65];
  __shared__ float Vs[64][36];
  __shared__ float sh_m[64], sh_l[64], sh_a[64];
  int t = threadIdx.x, ty = t >> 4, tx = t & 15;
  if (t < 64){ sh_m[t] = -1e30f; sh_l[t] = 0.f; }
  float O[8] = {0,0,0,0,0,0,0,0};
  int r8 = t >> 2, j0 = (t & 3) * 8;
  const float scale = 0.044194173824159216f;   // 1/sqrt(512)
  for (int s0 = 0; s0 < T_; s0 += 64) {
    float acc[4][4] = {};
    for (int e0 = 0; e0 < 512; e0 += 32) {
      #pragma unroll
      for (int u=0; u<2; u++){
        int idx = t + u*256;
        int r = idx >> 3, c4 = (idx & 7) * 4;
        *(float4*)&Qs[r][c4] = *(const float4*)(qbp + (size_t)(m0+r)*512 + e0 + c4);
        *(float4*)&Ks[r][c4] = *(const float4*)(kbp + (size_t)(s0+r)*512 + e0 + c4);
      }
      __syncthreads();
      #pragma unroll
      for (int kk=0; kk<32; kk++){
        float a0=Qs[ty*4+0][kk], a1=Qs[ty*4+1][kk], a2=Qs[ty*4+2][kk], a3=Qs[ty*4+3][kk];
        float b0=Ks[tx*4+0][kk], b1=Ks[tx*4+1][kk], b2=Ks[tx*4+2][kk], b3=Ks[tx*4+3][kk];
        acc[0][0]+=a0*b0; acc[0][1]+=a0*b1; acc[0][2]+=a0*b2; acc[0][3]+=a0*b3;
        acc[1][0]+=a1*b0; acc[1][1]+=a1*b1; acc[1][2]+=a1*b2; acc[1][3]+=a1*b3;
        acc[2][0]+=a2*b0; acc[2][1]+=a2*b1; acc[2][2]+=a2*b2; acc[2][3]+=a2*b3;
        acc[3][0]+=a3*b0; acc[3][1]+=a3*b1; acc[3][2]+=a3*b2; acc[3][3]+=a3*b3;
      }
      __syncthreads();
    }
    // V tile (64x32) + S tile to LDS
    #pragma unroll
    for (int u=0; u<2; u++){
      int idx = t + u*256;
      int r = idx >> 3, c4 = (idx & 7) * 4;
      *(float4*)&Vs[r][c4] = *(const float4*)(vbp + (size_t)(s0+r)*32 + c4);
    }
    #pragma unroll
    for (int i=0;i<4;i++)
      #pragma unroll
      for (int j=0;j<4;j++)
        Ss[ty*4+i][tx*4+j] = acc[i][j]*scale;
    __syncthreads();
    if (t < 64) {                    // online softmax row pass
      int r = t;
      float mo = sh_m[r], mt = -1e30f;
      for (int c=0;c<64;c++) mt = fmaxf(mt, Ss[r][c]);
      float mn = fmaxf(mo, mt);
      float al = __expf(mo - mn);
      float rs = 0.f;
      for (int c=0;c<64;c++){ float p = __expf(Ss[r][c]-mn); Ss[r][c]=p; rs+=p; }
      sh_l[r] = sh_l[r]*al + rs;
      sh_m[r] = mn; sh_a[r] = al;
    }
    __syncthreads();
    float al = sh_a[r8];
    #pragma unroll
    for (int j=0;j<8;j++) O[j] *= al;
    for (int c=0;c<64;c++){
      float p = Ss[r8][c];
      #pragma unroll
      for (int j=0;j<8;j++) O[j] += p * Vs[c][j0+j];
    }
    __syncthreads();
  }
  float linv = 1.f / sh_l[r8];
  #pragma unroll
  for (int j=0;j<8;j++){
    int cc = j0 + j, h = cc >> 2, qi = cc & 3;
    float o = O[j] * linv;
    float A = cAB[h*4+qi], Bv = cAB[32+h*4+qi];
    q32out[((size_t)b*T_ + m0 + r8)*32 + cc] = cosf(o)*A - sinf(o)*Bv;
  }
}

// ------------------- K3: attn_out proj (32 cols) + residual + LN1 + FFN circuit trig
__global__ __launch_bounds__(256) void k3_proj_ln(const float* __restrict__ x,
    const float* __restrict__ q32, const float* __restrict__ wo32,
    const float* __restrict__ g1, const float* __restrict__ b1,
    const float* __restrict__ cAB, float* __restrict__ x1, float* __restrict__ fbuf) {
  int tok = blockIdx.x, t = threadIdx.x;
  __shared__ float qrow[32];
  __shared__ float rs1[4], rs2[4], mv[2], shv[8];
  if (t < 32) qrow[t] = q32[(size_t)tok*32 + t];
  __syncthreads();
  float vals[2], ssum=0.f, ssq=0.f;
  #pragma unroll
  for (int u=0;u<2;u++){
    int e = t + u*256;
    float s = 0.f;
    const float4* wr = (const float4*)(wo32 + (size_t)e*32);
    #pragma unroll
    for (int c4=0;c4<8;c4++){
      float4 wv = wr[c4];
      float4 qv = *(float4*)&qrow[c4*4];
      s += wv.x*qv.x + wv.y*qv.y + wv.z*qv.z + wv.w*qv.w;
    }
    s += x[(size_t)tok*512 + e];
    vals[u]=s; ssum+=s; ssq+=s*s;
  }
  #pragma unroll
  for (int off=32; off>0; off>>=1){ ssum += __shfl_down(ssum,off); ssq += __shfl_down(ssq,off); }
  int wid = t >> 6;
  if ((t & 63) == 0){ rs1[wid]=ssum; rs2[wid]=ssq; }
  __syncthreads();
  if (t == 0){
    float a = rs1[0]+rs1[1]+rs1[2]+rs1[3];
    float b = rs2[0]+rs2[1]+rs2[2]+rs2[3];
    float mean = a * (1.f/512.f);
    float var  = b * (1.f/512.f) - mean*mean;
    mv[0]=mean; mv[1]=rsqrtf(var + 1e-5f);
  }
  __syncthreads();
  float mean=mv[0], rstd=mv[1];
  #pragma unroll
  for (int u=0;u<2;u++){
    int e = t + u*256;
    float nv = (vals[u]-mean)*rstd*g1[e] + b1[e];
    x1[(size_t)tok*512 + e] = nv;
    if (e < 8) shv[e] = nv;
  }
  __syncthreads();
  if (t < 8){
    float A = cAB[64+t], Bv = cAB[72+t];
    fbuf[(size_t)tok*8 + t] = cosf(shv[t])*A - sinf(shv[t])*Bv;
  }
}

// ----------------------- K4: out2 = relu(f @ w1^T) @ w2^T (h computed on the fly)
__global__ __launch_bounds__(256) void k4_ffn(const float* __restrict__ fbuf,
    const float* __restrict__ w1, const float* __restrict__ w2,
    float* __restrict__ out2) {
  int n0 = blockIdx.x * 64, m0 = blockIdx.y * 64;
  __shared__ float Fs[64][9];
  __shared__ float W1s[32][9];
  __shared__ float Hs[64][36];
  __shared__ float W2s[64][36];
  int t = threadIdx.x, ty = t >> 4, tx = t & 15;
  #pragma unroll
  for (int u=0;u<2;u++){
    int idx = t + u*256;                       // 0..511
    Fs[idx>>3][idx&7] = fbuf[(size_t)(m0 + (idx>>3))*8 + (idx&7)];
  }
  float acc[4][4] = {};
  int hm = t >> 2, hk0 = (t & 3) * 8;
  for (int k0 = 0; k0 < 2048; k0 += 32) {
    { int r = t >> 3, c = t & 7;
      W1s[r][c] = w1[(size_t)(k0+r)*8 + c]; }
    #pragma unroll
    for (int u=0;u<2;u++){
      int idx = t + u*256;
      int r = idx >> 3, c4 = (idx & 7) * 4;
      *(float4*)&W2s[r][c4] = *(const float4*)(w2 + (size_t)(n0+r)*2048 + k0 + c4);
    }
    __syncthreads();
    #pragma unroll
    for (int jj=0;jj<8;jj++){
      int kk = hk0 + jj;
      float h = 0.f;
      #pragma unroll
      for (int c=0;c<8;c++) h += Fs[hm][c]*W1s[kk][c];
      Hs[hm][kk] = fmaxf(h, 0.f);
    }
    __syncthreads();
    #pragma unroll
    for (int kk=0; kk<32; kk++){
      float a0=Hs[ty*4+0][kk], a1=Hs[ty*4+1][kk], a2=Hs[ty*4+2][kk], a3=Hs[ty*4+3][kk];
      float b0=W2s[tx*4+0][kk], b1=W2s[tx*4+1][kk], b2=W2s[tx*4+2][kk], b3=W2s[tx*4+3][kk];
      acc[0][0]+=a0*b0; acc[0][1]+=a0*b1; acc[0][2]+=a0*b2; acc[0][3]+=a0*b3;
      acc[1][0]+=a1*b0; acc[1][1]+=a1*b1; acc[1][2]+=a1*b2; acc[1][3]+=a1*b3;
      acc[2][0]+=a2*b0; acc[2][1]+=a2*b1; acc[2][2]+=a2*b2; acc[2][3]+=a2*b3;
      acc[3][0]+=a3*b0; acc[3][1]+=a3*b1; acc[3][2]+=a3*b2; acc[3][3]+=a3*b3;
    }
    __syncthreads();
  }
  #pragma unroll
  for (int i=0;i<4;i++){
    float4 v = make_float4(acc[i][0], acc[i][1], acc[i][2], acc[i][3]);
    *(float4*)(out2 + (size_t)(m0+ty*4+i)*512 + n0 + tx*4) = v;
  }
}

// --------------------------------------------- K5: out = LN(x1 + out2, g2, b2)
__global__ __launch_bounds__(256) void k5_ln2(const float* __restrict__ x1,
    const float* __restrict__ g2, const float* __restrict__ b2,
    float* __restrict__ out) {
  int tok = blockIdx.x, t = threadIdx.x;
  __shared__ float rs1[4], rs2[4], mv[2];
  float vals[2], ssum=0.f, ssq=0.f;
  #pragma unroll
  for (int u=0;u<2;u++){
    int e = t + u*256;
    float s = x1[(size_t)tok*512 + e] + out[(size_t)tok*512 + e];
    vals[u]=s; ssum+=s; ssq+=s*s;
  }
  #pragma unroll
  for (int off=32; off>0; off>>=1){ ssum += __shfl_down(ssum,off); ssq += __shfl_down(ssq,off); }
  int wid = t >> 6;
  if ((t & 63) == 0){ rs1[wid]=ssum; rs2[wid]=ssq; }
  __syncthreads();
  if (t == 0){
    float a = rs1[0]+rs1[1]+rs1[2]+rs1[3];
    float b = rs2[0]+rs2[1]+rs2[2]+rs2[3];
    float mean = a * (1.f/512.f);
    float var  = b * (1.f/512.f) - mean*mean;
    mv[0]=mean; mv[1]=rsqrtf(var + 1e-5f);
  }
  __syncthreads();
  float mean=mv[0], rstd=mv[1];
  #pragma unroll
  for (int u=0;u<2;u++){
    int e = t + u*256;
    out[(size_t)tok*512 + e] = (vals[u]-mean)*rstd*g2[e] + b2[e];
  }
}

// ---------------------------------------------------------------- launch
extern "C" void kernel_launch(void* const* d_in, const int* in_sizes, int n_in,
                              void* d_out, int out_size, void* d_ws, size_t ws_size,
                              hipStream_t stream) {
  const float* x  = (const float*)d_in[0];
  const float* wq = (const float*)d_in[1];
  const float* wk = (const float*)d_in[2];
  const float* wv = (const float*)d_in[3];
  const float* wo = (const float*)d_in[4];
  const float* hp = (const float*)d_in[5];
  const float* fp = (const float*)d_in[6];
  const float* w1 = (const float*)d_in[7];
  const float* w2 = (const float*)d_in[8];
  const float* g1 = (const float*)d_in[9];
  const float* b1 = (const float*)d_in[10];
  const float* g2 = (const float*)d_in[11];
  const float* b2 = (const float*)d_in[12];
  float* out = (float*)d_out;
  float* ws  = (float*)d_ws;

  // workspace layout (floats): ~105.5 MB total
  float* qb   = ws;                  // 8388608
  float* kb   = ws + 8388608;        // 8388608
  float* x1   = ws + 16777216;       // 8388608
  float* v32  = ws + 25165824;       // 524288
  float* q32  = ws + 25690112;       // 524288
  float* fbuf = ws + 26214400;       // 131072
  float* wo32 = ws + 26345472;       // 16384
  float* cAB  = ws + 26361856;       // 80

  k0_setup<<<1, 64, 0, stream>>>(hp, fp, wo, cAB, wo32);
  k1_qk  <<<dim3(8, 256, 2), 256, 0, stream>>>(x, wq, wk, qb, kb);
  k1_v32 <<<dim3(256),        256, 0, stream>>>(x, wv, v32);
  k2_attn<<<dim3(32, 8),      256, 0, stream>>>(qb, kb, v32, cAB, q32);
  k3_proj_ln<<<dim3(16384),   256, 0, stream>>>(x, q32, wo32, g1, b1, cAB, x1, fbuf);
  k4_ffn <<<dim3(8, 256),     256, 0, stream>>>(fbuf, w1, w2, out);
  k5_ln2 <<<dim3(16384),      256, 0, stream>>>(x1, g2, b2, out);
}

// Round 3
// 875.128 us; speedup vs baseline: 5.9109x; 5.9109x over previous
//
#include <hip/hip_runtime.h>
#include <hip/hip_bf16.h>
#include <math.h>

// B=8 T=2048 E=512 H=8 | NQ_H=4 NL=2 | NQ_F=8 FFN=2048
// Quantum circuits collapse to: qout_q = cos(x_q)*A_q - sin(x_q)*B_q (per-head/FFN consts).
// Round 3: identical structure to round 2, but PV MFMA uses the builtin
// __builtin_amdgcn_mfma_f32_16x16x16bf16_1k instead of raw inline asm — the asm
// version skipped the compiler's mandatory VALU<->MFMA hazard wait states (s_nop),
// reading stale registers => NaN.

#define B_   8
#define T_   2048
#define E_   512

typedef __attribute__((ext_vector_type(8))) short bf16x8;
typedef __attribute__((ext_vector_type(4))) short bf16x4;
typedef __attribute__((ext_vector_type(4))) float f32x4;

#define GLL16(g, l) __builtin_amdgcn_global_load_lds((const __attribute__((address_space(1))) void*)(g), (__attribute__((address_space(3))) void*)(l), 16, 0, 0)

__device__ inline unsigned short f2bf(float f){
  union { float f; unsigned u; } v; v.f = f;
  unsigned r = v.u + 0x7fff + ((v.u >> 16) & 1);   // RTNE
  return (unsigned short)(r >> 16);
}

// ---------------------------------------------------------------- K0: setup
__global__ void k0_setup(const float* __restrict__ hp, const float* __restrict__ fp,
                         const float* __restrict__ wo, float* __restrict__ cAB,
                         float* __restrict__ wo32) {
  __shared__ float fst[256];
  int t = threadIdx.x;
  if (t < 8) {                       // per-head 4-qubit circuits
    float st[16];
    #pragma unroll
    for (int i=0;i<16;i++) st[i]=0.f;
    st[0]=1.f;
    for (int l=0;l<2;l++){
      for (int q=0;q<4;q++){
        float th = 0.5f*hp[t*8 + l*4 + q];
        float c = cosf(th), s = sinf(th);
        int str = 1<<(3-q);
        for (int i=0;i<16;i++) if (!(i & str)) {
          float s0=st[i], s1=st[i|str];
          st[i]     = c*s0 - s*s1;
          st[i|str] = s*s0 + c*s1;
        }
      }
      for (int q=0;q<4;q++){
        int ctrl = (q<3)? q : 3, tgt = (q<3)? q+1 : 0;
        int cs = 1<<(3-ctrl), tsr = 1<<(3-tgt);
        for (int i=0;i<16;i++) if ((i&cs) && !(i&tsr)) {
          float tmp = st[i]; st[i]=st[i|tsr]; st[i|tsr]=tmp;
        }
      }
    }
    for (int q=0;q<4;q++){
      int str = 1<<(3-q);
      float A=0.f, Bv=0.f;
      for (int i=0;i<16;i++){
        A  += st[i]*st[i] * ((i&str)? -1.f : 1.f);
        Bv += st[i]*st[i^str];
      }
      cAB[t*4+q]    = A;
      cAB[32+t*4+q] = Bv;
    }
  }
  if (t == 8) {                      // FFN 8-qubit circuit
    for (int i=0;i<256;i++) fst[i]=0.f;
    fst[0]=1.f;
    for (int q=0;q<8;q++){
      float th = 0.5f*fp[q];
      float c = cosf(th), s = sinf(th);
      int str = 1<<(7-q);
      for (int i=0;i<256;i++) if (!(i & str)) {
        float s0=fst[i], s1=fst[i|str];
        fst[i]     = c*s0 - s*s1;
        fst[i|str] = s*s0 + c*s1;
      }
    }
    for (int q=0;q<8;q++){
      int ctrl = (q<7)? q : 7, tgt = (q<7)? q+1 : 0;
      int cs = 1<<(7-ctrl), tsr = 1<<(7-tgt);
      for (int i=0;i<256;i++) if ((i&cs) && !(i&tsr)) {
        float tmp = fst[i]; fst[i]=fst[i|tsr]; fst[i|tsr]=tmp;
      }
    }
    for (int q=0;q<8;q++){
      int str = 1<<(7-q);
      float A=0.f, Bv=0.f;
      for (int i=0;i<256;i++){
        A  += fst[i]*fst[i] * ((i&str)? -1.f : 1.f);
        Bv += fst[i]*fst[i^str];
      }
      cAB[64+q] = A;
      cAB[72+q] = Bv;
    }
  }
  for (int idx = t; idx < 512*32; idx += 64){
    int e = idx >> 5, c = idx & 31;
    wo32[idx] = wo[(size_t)e*512 + (c>>2)*64 + (c&3)];
  }
}

// ------------------------------------------------------------ casts to bf16
__global__ void kc_x(const float* __restrict__ x, unsigned short* __restrict__ xb){
  int i = blockIdx.x*256 + threadIdx.x;           // 1048576 chunks of 8
  const float4* p = (const float4*)x + (size_t)i*2;
  float4 a = p[0], b = p[1];
  union { unsigned short h[8]; uint4 u; } o;
  o.h[0]=f2bf(a.x); o.h[1]=f2bf(a.y); o.h[2]=f2bf(a.z); o.h[3]=f2bf(a.w);
  o.h[4]=f2bf(b.x); o.h[5]=f2bf(b.y); o.h[6]=f2bf(b.z); o.h[7]=f2bf(b.w);
  ((uint4*)xb)[i] = o.u;
}

__global__ void kc_w(const float* __restrict__ wq, const float* __restrict__ wk,
                     const float* __restrict__ w2, unsigned short* __restrict__ wqkb,
                     unsigned short* __restrict__ w2b){
  int i = blockIdx.x*256 + threadIdx.x;           // 196608 chunks of 8
  const float* src; unsigned short* dst; float s = 1.f;
  if (i < 65536){
    int row = i >> 6, c8 = (i & 63)*8;
    if (row < 512){ src = wq + (size_t)row*512 + c8; s = 0.044194173824159216f; } // fold 1/sqrt(E)
    else          { src = wk + (size_t)(row-512)*512 + c8; }
    dst = wqkb + (size_t)row*512 + c8;
  } else {
    int j = i - 65536;
    src = w2 + (size_t)j*8; dst = w2b + (size_t)j*8;
  }
  float4 a = *(const float4*)src, b = *(const float4*)(src+4);
  union { unsigned short h[8]; uint4 u; } o;
  o.h[0]=f2bf(a.x*s); o.h[1]=f2bf(a.y*s); o.h[2]=f2bf(a.z*s); o.h[3]=f2bf(a.w*s);
  o.h[4]=f2bf(b.x*s); o.h[5]=f2bf(b.y*s); o.h[6]=f2bf(b.z*s); o.h[7]=f2bf(b.w*s);
  *(uint4*)dst = o.u;
}

// -------------------------------- m97-style MFMA GEMM: C = A (MxK) * Bw^T (NxK)
template<int K, int LDC, bool OUTBF>
__global__ __launch_bounds__(256,2) void gemm_bt(
    const unsigned short* __restrict__ A, const unsigned short* __restrict__ Bw,
    void* __restrict__ C, int m_base){
  __shared__ __align__(16) char sm[16384];
  char* As = sm; char* Bs = sm + 8192;             // [128][32] bf16, 64B rows, xor-swizzled
  int t = threadIdx.x, w = t>>6, l = t&63;
  int lr = l&15, quad = l>>4;
  int m0 = blockIdx.y*128, n0 = blockIdx.x*128;
  int wr = (w>>1)*64, wc = (w&1)*64;
  f32x4 acc[4][4] = {};
  for (int k0 = 0; k0 < K; k0 += 32){
    __syncthreads();
    #pragma unroll
    for (int c = 0; c < 2; ++c){
      int ch = c*256 + t, row = ch>>2, sw = ch&3, lc = sw ^ ((row>>1)&3);
      GLL16(A  + (size_t)(m0+row)*K + k0 + lc*8, As + c*4096 + w*1024);
      GLL16(Bw + (size_t)(n0+row)*K + k0 + lc*8, Bs + c*4096 + w*1024);
    }
    __syncthreads();
    bf16x8 af[4], bg[4];
    #pragma unroll
    for (int i=0;i<4;++i){
      int ra = wr + i*16 + lr;
      af[i] = *(const bf16x8*)(As + ra*64 + (quad ^ ((ra>>1)&3))*16);
      int rb = wc + i*16 + lr;
      bg[i] = *(const bf16x8*)(Bs + rb*64 + (quad ^ ((rb>>1)&3))*16);
    }
    #pragma unroll
    for (int i=0;i<4;++i)
      #pragma unroll
      for (int j=0;j<4;++j)
        acc[i][j] = __builtin_amdgcn_mfma_f32_16x16x32_bf16(af[i], bg[j], acc[i][j], 0,0,0);
  }
  #pragma unroll
  for (int i=0;i<4;++i)
    #pragma unroll
    for (int j=0;j<4;++j)
      #pragma unroll
      for (int r=0;r<4;++r){
        size_t row = (size_t)(m_base + m0 + wr + i*16 + quad*4 + r);
        int col = n0 + wc + j*16 + lr;
        if constexpr (OUTBF) ((unsigned short*)C)[row*LDC + col] = f2bf(acc[i][j][r]);
        else                 ((float*)C)[row*LDC + col] = acc[i][j][r];
      }
}

// ------------------------------------- K1v: v32t[b][c][s] = bf16(x @ wv[used]^T)
__global__ __launch_bounds__(256) void k1_v32(const float* __restrict__ x,
    const float* __restrict__ wv, unsigned short* __restrict__ v32t) {
  int m0 = blockIdx.x * 64;
  __shared__ float Xs[64][36];
  __shared__ float Ws[32][36];
  int t = threadIdx.x;
  int m = t >> 2, c0 = (t & 3) * 8;
  float acc[8] = {};
  for (int k0 = 0; k0 < 512; k0 += 32) {
    #pragma unroll
    for (int u=0; u<2; u++){
      int idx = t + u*256;
      int r = idx >> 3, c4 = (idx & 7) * 4;
      *(float4*)&Xs[r][c4] = *(const float4*)(x + (size_t)(m0+r)*512 + k0 + c4);
    }
    { int r = t >> 3, c4 = (t & 7) * 4;
      int wrow = (r>>2)*64 + (r&3);
      *(float4*)&Ws[r][c4] = *(const float4*)(wv + (size_t)wrow*512 + k0 + c4);
    }
    __syncthreads();
    #pragma unroll
    for (int kk=0; kk<32; kk++){
      float xv = Xs[m][kk];
      #pragma unroll
      for (int j=0;j<8;j++) acc[j] += xv * Ws[c0+j][kk];
    }
    __syncthreads();
  }
  int tok = m0 + m, bb = tok >> 11, s = tok & 2047;
  #pragma unroll
  for (int j=0;j<8;j++)
    v32t[((size_t)(bb*32 + c0 + j))*2048 + s] = f2bf(acc[j]);
}

// -------------------- K2: MFMA flash attention (S^T trick) + circuit trig epilogue
__global__ __launch_bounds__(256,1) void k2_attn(
    const unsigned short* __restrict__ qkb, const unsigned short* __restrict__ v32t,
    const float* __restrict__ cAB, float* __restrict__ q32out){
  __shared__ __align__(16) char sm[38912];
  char* Qc  = sm;            // [64][32] bf16 swizzled (4 KB)
  char* Ks  = sm + 4096;     // [256][32] bf16 swizzled (16 KB)
  char* Vts = sm + 20480;    // [32][256+8] bf16, 528B rows (16.5 KB)
  float* OtL = (float*)sm;           // merge overlay: [4][64][36] f32
  float* mL  = (float*)(sm + 36864); // [4][64]
  float* lL  = (float*)(sm + 37888); // [4][64]

  int t = threadIdx.x, w = t>>6, l = t&63;
  int lr = l & 15, quad = l >> 4;
  int b = blockIdx.y, m0 = blockIdx.x*64;
  size_t bT = (size_t)b*2048;
  const char* qbase = (const char*)qkb + (bT + m0)*2048;       // q cols 0-511 (pre-scaled)
  const char* vbase = (const char*)v32t + (size_t)b*32*4096;

  f32x4 Ot[2][4] = {};
  float mold[4] = {-1e30f,-1e30f,-1e30f,-1e30f};
  float lsum[4] = {0.f,0.f,0.f,0.f};

  for (int step = 0; step < 8; ++step){
    int s0 = step*256;
    const char* kbase = (const char*)qkb + (bT + s0)*2048 + 1024; // k cols 512-1023
    __syncthreads();
    { // stage V^T tile [32 vcols][256 scols]
      int j = t>>3, seg = t&7;
      const uint4* vs = (const uint4*)(vbase + (size_t)j*4096 + (s0 + seg*32)*2);
      uint4* vd = (uint4*)(Vts + j*528 + seg*64);
      vd[0]=vs[0]; vd[1]=vs[1]; vd[2]=vs[2]; vd[3]=vs[3];
    }
    f32x4 acc[4][4] = {};   // S^T tile: acc[si][qj], sc=w*64+si*16+quad*4+r, qr=qj*16+lr
    for (int ec = 0; ec < 16; ++ec){
      __syncthreads();
      { int row = t>>2, sw = t&3, lc = sw ^ ((row>>1)&3);        // stage Q chunk [64][32]
        GLL16(qbase + (size_t)row*2048 + ec*64 + lc*16, Qc + w*1024); }
      #pragma unroll
      for (int rd = 0; rd < 4; ++rd){                            // stage K chunk [256][32]
        int ch = rd*256 + t, row = ch>>2, sw = ch&3, lc = sw ^ ((row>>1)&3);
        GLL16(kbase + (size_t)row*2048 + ec*64 + lc*16, Ks + rd*4096 + w*1024);
      }
      __syncthreads();
      bf16x8 af[4], bq[4];
      #pragma unroll
      for (int si = 0; si < 4; ++si){
        int row = w*64 + si*16 + lr;
        af[si] = *(const bf16x8*)(Ks + row*64 + (quad ^ ((row>>1)&3))*16);
      }
      #pragma unroll
      for (int qj = 0; qj < 4; ++qj){
        int row = qj*16 + lr;
        bq[qj] = *(const bf16x8*)(Qc + row*64 + (quad ^ ((row>>1)&3))*16);
      }
      #pragma unroll
      for (int si = 0; si < 4; ++si)
        #pragma unroll
        for (int qj = 0; qj < 4; ++qj)   // S^T = K * Q^T
          acc[si][qj] = __builtin_amdgcn_mfma_f32_16x16x32_bf16(af[si], bq[qj], acc[si][qj], 0,0,0);
    }
    // online softmax over sc (rows of S^T) + PV from registers
    bf16x4 aV[2][4];
    #pragma unroll
    for (int vt=0; vt<2; ++vt)
      #pragma unroll
      for (int si=0; si<4; ++si)
        aV[vt][si] = *(const bf16x4*)(Vts + (vt*16+lr)*528 + (w*64 + si*16 + quad*4)*2);
    #pragma unroll
    for (int qj=0; qj<4; ++qj){
      float mt = -1e30f;
      #pragma unroll
      for (int si=0; si<4; ++si)
        #pragma unroll
        for (int r=0;r<4;++r) mt = fmaxf(mt, acc[si][qj][r]);
      mt = fmaxf(mt, __shfl_xor(mt, 16));
      mt = fmaxf(mt, __shfl_xor(mt, 32));
      float mn = fmaxf(mold[qj], mt);
      float al = __expf(mold[qj] - mn);
      mold[qj] = mn;
      float rs = 0.f;
      #pragma unroll
      for (int si=0; si<4; ++si)
        #pragma unroll
        for (int r=0;r<4;++r){
          float p = __expf(acc[si][qj][r] - mn);
          acc[si][qj][r] = p; rs += p;
        }
      rs += __shfl_xor(rs, 16); rs += __shfl_xor(rs, 32);
      lsum[qj] = lsum[qj]*al + rs;
      Ot[0][qj] *= al; Ot[1][qj] *= al;
      #pragma unroll
      for (int si=0; si<4; ++si){
        bf16x4 pb;                                  // P^T in exact B-operand layout
        pb[0]=(short)f2bf(acc[si][qj][0]); pb[1]=(short)f2bf(acc[si][qj][1]);
        pb[2]=(short)f2bf(acc[si][qj][2]); pb[3]=(short)f2bf(acc[si][qj][3]);
        Ot[0][qj] = __builtin_amdgcn_mfma_f32_16x16x16bf16_1k(aV[0][si], pb, Ot[0][qj], 0,0,0);
        Ot[1][qj] = __builtin_amdgcn_mfma_f32_16x16x16bf16_1k(aV[1][si], pb, Ot[1][qj], 0,0,0);
      }
    }
  }
  // merge 4 per-wave partial streams
  __syncthreads();
  #pragma unroll
  for (int qj=0; qj<4; ++qj){
    if (quad == 0){ mL[w*64 + qj*16 + lr] = mold[qj]; lL[w*64 + qj*16 + lr] = lsum[qj]; }
    *(f32x4*)(OtL + (size_t)(w*64 + qj*16 + lr)*36 + quad*4)      = Ot[0][qj];
    *(f32x4*)(OtL + (size_t)(w*64 + qj*16 + lr)*36 + 16 + quad*4) = Ot[1][qj];
  }
  __syncthreads();
  {
    int qr = t>>2, vg = (t&3)*8;
    float M = -1e30f;
    #pragma unroll
    for (int w4=0; w4<4; ++w4) M = fmaxf(M, mL[w4*64+qr]);
    float L = 0.f; float o[8] = {};
    #pragma unroll
    for (int w4=0; w4<4; ++w4){
      float a = __expf(mL[w4*64+qr] - M);
      L += a * lL[w4*64+qr];
      const float* Op = OtL + (size_t)(w4*64+qr)*36 + vg;
      #pragma unroll
      for (int j=0;j<8;++j) o[j] += a*Op[j];
    }
    float inv = 1.f/L;
    float res[8];
    #pragma unroll
    for (int j=0;j<8;++j){
      int cc = vg+j;
      float ov = o[j]*inv;
      res[j] = cosf(ov)*cAB[cc] - sinf(ov)*cAB[32+cc];
    }
    float* dst = q32out + ((size_t)bT + m0 + qr)*32 + vg;
    *(float4*)dst     = make_float4(res[0],res[1],res[2],res[3]);
    *(float4*)(dst+4) = make_float4(res[4],res[5],res[6],res[7]);
  }
}

// ------------------- K3: attn proj (32 cols) + residual + LN1 + FFN circuit trig
__global__ __launch_bounds__(256) void k3_proj_ln(const float* __restrict__ x,
    const float* __restrict__ q32, const float* __restrict__ wo32,
    const float* __restrict__ g1, const float* __restrict__ b1,
    const float* __restrict__ cAB, float* __restrict__ x1, float* __restrict__ fbuf) {
  int tok = blockIdx.x, t = threadIdx.x;
  __shared__ float qrow[32];
  __shared__ float rs1[4], rs2[4], mv[2], shv[8];
  if (t < 32) qrow[t] = q32[(size_t)tok*32 + t];
  __syncthreads();
  float vals[2], ssum=0.f, ssq=0.f;
  #pragma unroll
  for (int u=0;u<2;u++){
    int e = t + u*256;
    float s = 0.f;
    const float4* wr = (const float4*)(wo32 + (size_t)e*32);
    #pragma unroll
    for (int c4=0;c4<8;c4++){
      float4 wv = wr[c4];
      float4 qv = *(float4*)&qrow[c4*4];
      s += wv.x*qv.x + wv.y*qv.y + wv.z*qv.z + wv.w*qv.w;
    }
    s += x[(size_t)tok*512 + e];
    vals[u]=s; ssum+=s; ssq+=s*s;
  }
  #pragma unroll
  for (int off=32; off>0; off>>=1){ ssum += __shfl_down(ssum,off); ssq += __shfl_down(ssq,off); }
  int wid = t >> 6;
  if ((t & 63) == 0){ rs1[wid]=ssum; rs2[wid]=ssq; }
  __syncthreads();
  if (t == 0){
    float a = rs1[0]+rs1[1]+rs1[2]+rs1[3];
    float b = rs2[0]+rs2[1]+rs2[2]+rs2[3];
    float mean = a * (1.f/512.f);
    float var  = b * (1.f/512.f) - mean*mean;
    mv[0]=mean; mv[1]=rsqrtf(var + 1e-5f);
  }
  __syncthreads();
  float mean=mv[0], rstd=mv[1];
  #pragma unroll
  for (int u=0;u<2;u++){
    int e = t + u*256;
    float nv = (vals[u]-mean)*rstd*g1[e] + b1[e];
    x1[(size_t)tok*512 + e] = nv;
    if (e < 8) shv[e] = nv;
  }
  __syncthreads();
  if (t < 8){
    float A = cAB[64+t], Bv = cAB[72+t];
    fbuf[(size_t)tok*8 + t] = cosf(shv[t])*A - sinf(shv[t])*Bv;
  }
}

// -------------------- K4a: Hb = bf16(relu(f @ w1^T)) for an 8192-row half
__global__ void k4a(const float* __restrict__ fbuf, const float* __restrict__ w1,
                    unsigned short* __restrict__ Hb, int row0){
  int i = blockIdx.x*256 + threadIdx.x;       // 2097152 chunks of 8 cols
  int tok = i >> 8;
  int c8 = (i & 255) * 8;
  const float* f = fbuf + (size_t)(row0 + tok)*8;
  float fv[8];
  #pragma unroll
  for (int c=0;c<8;c++) fv[c] = f[c];
  union { unsigned short h[8]; uint4 u; } o;
  #pragma unroll
  for (int j=0;j<8;j++){
    const float* wr = w1 + (size_t)(c8+j)*8;
    float s = 0.f;
    #pragma unroll
    for (int c=0;c<8;c++) s += fv[c]*wr[c];
    o.h[j] = f2bf(fmaxf(s, 0.f));
  }
  ((uint4*)Hb)[(size_t)tok*256 + (i & 255)] = o.u;
}

// --------------------------------------------- K5: out = LN(x1 + out2, g2, b2)
__global__ __launch_bounds__(256) void k5_ln2(const float* __restrict__ x1,
    const float* __restrict__ g2, const float* __restrict__ b2,
    float* __restrict__ out) {
  int tok = blockIdx.x, t = threadIdx.x;
  __shared__ float rs1[4], rs2[4], mv[2];
  float vals[2], ssum=0.f, ssq=0.f;
  #pragma unroll
  for (int u=0;u<2;u++){
    int e = t + u*256;
    float s = x1[(size_t)tok*512 + e] + out[(size_t)tok*512 + e];
    vals[u]=s; ssum+=s; ssq+=s*s;
  }
  #pragma unroll
  for (int off=32; off>0; off>>=1){ ssum += __shfl_down(ssum,off); ssq += __shfl_down(ssq,off); }
  int wid = t >> 6;
  if ((t & 63) == 0){ rs1[wid]=ssum; rs2[wid]=ssq; }
  __syncthreads();
  if (t == 0){
    float a = rs1[0]+rs1[1]+rs1[2]+rs1[3];
    float b = rs2[0]+rs2[1]+rs2[2]+rs2[3];
    float mean = a * (1.f/512.f);
    float var  = b * (1.f/512.f) - mean*mean;
    mv[0]=mean; mv[1]=rsqrtf(var + 1e-5f);
  }
  __syncthreads();
  float mean=mv[0], rstd=mv[1];
  #pragma unroll
  for (int u=0;u<2;u++){
    int e = t + u*256;
    out[(size_t)tok*512 + e] = (vals[u]-mean)*rstd*g2[e] + b2[e];
  }
}

// ---------------------------------------------------------------- launch
extern "C" void kernel_launch(void* const* d_in, const int* in_sizes, int n_in,
                              void* d_out, int out_size, void* d_ws, size_t ws_size,
                              hipStream_t stream) {
  const float* x  = (const float*)d_in[0];
  const float* wq = (const float*)d_in[1];
  const float* wk = (const float*)d_in[2];
  const float* wv = (const float*)d_in[3];
  const float* wo = (const float*)d_in[4];
  const float* hp = (const float*)d_in[5];
  const float* fp = (const float*)d_in[6];
  const float* w1 = (const float*)d_in[7];
  const float* w2 = (const float*)d_in[8];
  const float* g1 = (const float*)d_in[9];
  const float* b1 = (const float*)d_in[10];
  const float* g2 = (const float*)d_in[11];
  const float* b2 = (const float*)d_in[12];
  float* out = (float*)d_out;
  float* ws  = (float*)d_ws;

  // workspace layout (float slots), ~90.8 MB total:
  unsigned short* qkb  = (unsigned short*)(ws);             // [16384][1024] bf16 (33.5MB); reused as Hb half
  float*          x1   = ws + 8388608;                      // [16384][512] f32
  unsigned short* xb   = (unsigned short*)(ws + 16777216);  // [16384][512] bf16
  unsigned short* wqkb = (unsigned short*)(ws + 20971520);  // [1024][512] bf16 (wq scaled ; wk)
  unsigned short* w2b  = (unsigned short*)(ws + 21233664);  // [512][2048] bf16
  unsigned short* v32t = (unsigned short*)(ws + 21757952);  // [8][32][2048] bf16
  float*          q32  = ws + 22020096;                     // [16384][32] f32
  float*          fbuf = ws + 22544384;                     // [16384][8] f32
  float*          wo32 = ws + 22675456;                     // [512][32] f32
  float*          cAB  = ws + 22691840;                     // 80 consts
  unsigned short* Hb   = (unsigned short*)(ws);             // overlay (qkb dead after k2)

  k0_setup<<<1, 64, 0, stream>>>(hp, fp, wo, cAB, wo32);
  kc_x<<<4096, 256, 0, stream>>>(x, xb);
  kc_w<<<768, 256, 0, stream>>>(wq, wk, w2, wqkb, w2b);
  gemm_bt<512,1024,true><<<dim3(8,128), 256, 0, stream>>>(xb, wqkb, qkb, 0);
  k1_v32<<<256, 256, 0, stream>>>(x, wv, v32t);
  k2_attn<<<dim3(32,8), 256, 0, stream>>>(qkb, v32t, cAB, q32);
  k3_proj_ln<<<16384, 256, 0, stream>>>(x, q32, wo32, g1, b1, cAB, x1, fbuf);
  k4a<<<8192, 256, 0, stream>>>(fbuf, w1, Hb, 0);
  gemm_bt<2048,512,false><<<dim3(4,64), 256, 0, stream>>>(Hb, w2b, out, 0);
  k4a<<<8192, 256, 0, stream>>>(fbuf, w1, Hb, 8192);
  gemm_bt<2048,512,false><<<dim3(4,64), 256, 0, stream>>>(Hb, w2b, out, 8192);
  k5_ln2<<<16384, 256, 0, stream>>>(x1, g2, b2, out);
}

// Round 4
// 693.411 us; speedup vs baseline: 7.4599x; 1.2621x over previous
//
#include <hip/hip_runtime.h>
#include <hip/hip_bf16.h>
#include <math.h>

// B=8 T=2048 E=512 H=8 | NQ_H=4 NL=2 | NQ_F=8 FFN=2048
// Quantum circuits collapse to: qout_q = cos(x_q)*A_q - sin(x_q)*B_q (per-head/FFN consts).
// Round 4: k0_setup was 232 us (27% of total, top-5 all k0) — 1-thread 8-qubit sim +
// 64-lane scattered wo32 pack. Now: 256-thread parallel state-vector sim, 16-block
// coalesced float4 wo32 pack, and kc_x/kc_w merged into one dispatch. MFMA kernels
// (gemm_bt / k2_attn) are byte-identical to the round-3 verified versions.

#define B_   8
#define T_   2048
#define E_   512

typedef __attribute__((ext_vector_type(8))) short bf16x8;
typedef __attribute__((ext_vector_type(4))) short bf16x4;
typedef __attribute__((ext_vector_type(4))) float f32x4;

#define GLL16(g, l) __builtin_amdgcn_global_load_lds((const __attribute__((address_space(1))) void*)(g), (__attribute__((address_space(3))) void*)(l), 16, 0, 0)

__device__ inline unsigned short f2bf(float f){
  union { float f; unsigned u; } v; v.f = f;
  unsigned r = v.u + 0x7fff + ((v.u >> 16) & 1);   // RTNE
  return (unsigned short)(r >> 16);
}

// ------------------------------------------- K0 (parallel): circuits + wo32 pack
__global__ __launch_bounds__(256) void k0_setup(const float* __restrict__ hp,
                         const float* __restrict__ fp,
                         const float* __restrict__ wo, float* __restrict__ cAB,
                         float* __restrict__ wo32) {
  int t = threadIdx.x, bi = blockIdx.x;
  if (bi > 0) {                      // blocks 1..16: pack wo32 (coalesced float4)
    int gid = (bi-1)*256 + t;        // 4096 float4 = 512 rows x 8 groups
    int e = gid >> 3, c4 = gid & 7;  // wo cols c4*64 .. c4*64+3 are contiguous
    float4 v = *(const float4*)(wo + (size_t)e*512 + c4*64);
    *(float4*)(wo32 + (size_t)e*32 + c4*4) = v;
    return;
  }
  // ---- block 0: FFN 8-qubit circuit, one amplitude per thread ----
  __shared__ float fst[256], tmp[256], ra[256], rb[256];
  fst[t] = (t == 0) ? 1.f : 0.f;
  __syncthreads();
  #pragma unroll
  for (int q = 0; q < 8; ++q) {      // RY layer (params row 0)
    int str = 1 << (7-q);
    float th = 0.5f * fp[q];
    float c = cosf(th), s = sinf(th);
    float self = fst[t], part = fst[t ^ str];
    float nv = (t & str) ? (c*self + s*part) : (c*self - s*part);
    __syncthreads();
    tmp[t] = nv;
    __syncthreads();
    fst[t] = tmp[t];
    __syncthreads();
  }
  #pragma unroll
  for (int g = 0; g < 8; ++g) {      // CNOT chain + ring
    int ctrl = (g < 7) ? g : 7, tgt = (g < 7) ? g+1 : 0;
    int cs = 1 << (7-ctrl), tsr = 1 << (7-tgt);
    float nv = fst[(t & cs) ? (t ^ tsr) : t];
    __syncthreads();
    fst[t] = nv;
    __syncthreads();
  }
  #pragma unroll
  for (int q = 0; q < 8; ++q) {      // <Z_q>, <X_q>
    int str = 1 << (7-q);
    float a = fst[t]*fst[t] * ((t & str) ? -1.f : 1.f);
    float b = fst[t]*fst[t ^ str];
    ra[t] = a; rb[t] = b;
    __syncthreads();
    for (int off = 128; off > 0; off >>= 1){
      if (t < off){ ra[t] += ra[t+off]; rb[t] += rb[t+off]; }
      __syncthreads();
    }
    if (t == 0){ cAB[64+q] = ra[0]; cAB[72+q] = rb[0]; }
    __syncthreads();
  }
  // ---- per-head 4-qubit circuits: 8 parallel threads, 16 amps in registers ----
  if (t < 8) {
    float st[16];
    #pragma unroll
    for (int i=0;i<16;i++) st[i]=0.f;
    st[0]=1.f;
    for (int l=0;l<2;l++){
      for (int q=0;q<4;q++){
        float th = 0.5f*hp[t*8 + l*4 + q];
        float c = cosf(th), s = sinf(th);
        int str = 1<<(3-q);
        for (int i=0;i<16;i++) if (!(i & str)) {
          float s0=st[i], s1=st[i|str];
          st[i]     = c*s0 - s*s1;
          st[i|str] = s*s0 + c*s1;
        }
      }
      for (int q=0;q<4;q++){
        int ctrl = (q<3)? q : 3, tgt = (q<3)? q+1 : 0;
        int cs = 1<<(3-ctrl), tsr = 1<<(3-tgt);
        for (int i=0;i<16;i++) if ((i&cs) && !(i&tsr)) {
          float tt = st[i]; st[i]=st[i|tsr]; st[i|tsr]=tt;
        }
      }
    }
    for (int q=0;q<4;q++){
      int str = 1<<(3-q);
      float A=0.f, Bv=0.f;
      for (int i=0;i<16;i++){
        A  += st[i]*st[i] * ((i&str)? -1.f : 1.f);
        Bv += st[i]*st[i^str];
      }
      cAB[t*4+q]    = A;
      cAB[32+t*4+q] = Bv;
    }
  }
}

// -------------------------------------- merged casts to bf16 (xb | wqkb,w2b)
__global__ __launch_bounds__(256) void kc_cast(const float* __restrict__ x,
                     const float* __restrict__ wq, const float* __restrict__ wk,
                     const float* __restrict__ w2, unsigned short* __restrict__ xb,
                     unsigned short* __restrict__ wqkb, unsigned short* __restrict__ w2b){
  int bi = blockIdx.x;
  if (bi < 4096) {                                 // x -> xb: 1048576 chunks of 8
    int i = bi*256 + threadIdx.x;
    const float4* p = (const float4*)x + (size_t)i*2;
    float4 a = p[0], b = p[1];
    union { unsigned short h[8]; uint4 u; } o;
    o.h[0]=f2bf(a.x); o.h[1]=f2bf(a.y); o.h[2]=f2bf(a.z); o.h[3]=f2bf(a.w);
    o.h[4]=f2bf(b.x); o.h[5]=f2bf(b.y); o.h[6]=f2bf(b.z); o.h[7]=f2bf(b.w);
    ((uint4*)xb)[i] = o.u;
    return;
  }
  int i = (bi-4096)*256 + threadIdx.x;             // 196608 chunks of 8
  const float* src; unsigned short* dst; float s = 1.f;
  if (i < 65536){
    int row = i >> 6, c8 = (i & 63)*8;
    if (row < 512){ src = wq + (size_t)row*512 + c8; s = 0.044194173824159216f; } // fold 1/sqrt(E)
    else          { src = wk + (size_t)(row-512)*512 + c8; }
    dst = wqkb + (size_t)row*512 + c8;
  } else {
    int j = i - 65536;
    src = w2 + (size_t)j*8; dst = w2b + (size_t)j*8;
  }
  float4 a = *(const float4*)src, b = *(const float4*)(src+4);
  union { unsigned short h[8]; uint4 u; } o;
  o.h[0]=f2bf(a.x*s); o.h[1]=f2bf(a.y*s); o.h[2]=f2bf(a.z*s); o.h[3]=f2bf(a.w*s);
  o.h[4]=f2bf(b.x*s); o.h[5]=f2bf(b.y*s); o.h[6]=f2bf(b.z*s); o.h[7]=f2bf(b.w*s);
  *(uint4*)dst = o.u;
}

// -------------------------------- m97-style MFMA GEMM: C = A (MxK) * Bw^T (NxK)
template<int K, int LDC, bool OUTBF>
__global__ __launch_bounds__(256,2) void gemm_bt(
    const unsigned short* __restrict__ A, const unsigned short* __restrict__ Bw,
    void* __restrict__ C, int m_base){
  __shared__ __align__(16) char sm[16384];
  char* As = sm; char* Bs = sm + 8192;             // [128][32] bf16, 64B rows, xor-swizzled
  int t = threadIdx.x, w = t>>6, l = t&63;
  int lr = l&15, quad = l>>4;
  int m0 = blockIdx.y*128, n0 = blockIdx.x*128;
  int wr = (w>>1)*64, wc = (w&1)*64;
  f32x4 acc[4][4] = {};
  for (int k0 = 0; k0 < K; k0 += 32){
    __syncthreads();
    #pragma unroll
    for (int c = 0; c < 2; ++c){
      int ch = c*256 + t, row = ch>>2, sw = ch&3, lc = sw ^ ((row>>1)&3);
      GLL16(A  + (size_t)(m0+row)*K + k0 + lc*8, As + c*4096 + w*1024);
      GLL16(Bw + (size_t)(n0+row)*K + k0 + lc*8, Bs + c*4096 + w*1024);
    }
    __syncthreads();
    bf16x8 af[4], bg[4];
    #pragma unroll
    for (int i=0;i<4;++i){
      int ra = wr + i*16 + lr;
      af[i] = *(const bf16x8*)(As + ra*64 + (quad ^ ((ra>>1)&3))*16);
      int rb = wc + i*16 + lr;
      bg[i] = *(const bf16x8*)(Bs + rb*64 + (quad ^ ((rb>>1)&3))*16);
    }
    #pragma unroll
    for (int i=0;i<4;++i)
      #pragma unroll
      for (int j=0;j<4;++j)
        acc[i][j] = __builtin_amdgcn_mfma_f32_16x16x32_bf16(af[i], bg[j], acc[i][j], 0,0,0);
  }
  #pragma unroll
  for (int i=0;i<4;++i)
    #pragma unroll
    for (int j=0;j<4;++j)
      #pragma unroll
      for (int r=0;r<4;++r){
        size_t row = (size_t)(m_base + m0 + wr + i*16 + quad*4 + r);
        int col = n0 + wc + j*16 + lr;
        if constexpr (OUTBF) ((unsigned short*)C)[row*LDC + col] = f2bf(acc[i][j][r]);
        else                 ((float*)C)[row*LDC + col] = acc[i][j][r];
      }
}

// ------------------------------------- K1v: v32t[b][c][s] = bf16(x @ wv[used]^T)
__global__ __launch_bounds__(256) void k1_v32(const float* __restrict__ x,
    const float* __restrict__ wv, unsigned short* __restrict__ v32t) {
  int m0 = blockIdx.x * 64;
  __shared__ float Xs[64][36];
  __shared__ float Ws[32][36];
  int t = threadIdx.x;
  int m = t >> 2, c0 = (t & 3) * 8;
  float acc[8] = {};
  for (int k0 = 0; k0 < 512; k0 += 32) {
    #pragma unroll
    for (int u=0; u<2; u++){
      int idx = t + u*256;
      int r = idx >> 3, c4 = (idx & 7) * 4;
      *(float4*)&Xs[r][c4] = *(const float4*)(x + (size_t)(m0+r)*512 + k0 + c4);
    }
    { int r = t >> 3, c4 = (t & 7) * 4;
      int wrow = (r>>2)*64 + (r&3);
      *(float4*)&Ws[r][c4] = *(const float4*)(wv + (size_t)wrow*512 + k0 + c4);
    }
    __syncthreads();
    #pragma unroll
    for (int kk=0; kk<32; kk++){
      float xv = Xs[m][kk];
      #pragma unroll
      for (int j=0;j<8;j++) acc[j] += xv * Ws[c0+j][kk];
    }
    __syncthreads();
  }
  int tok = m0 + m, bb = tok >> 11, s = tok & 2047;
  #pragma unroll
  for (int j=0;j<8;j++)
    v32t[((size_t)(bb*32 + c0 + j))*2048 + s] = f2bf(acc[j]);
}

// -------------------- K2: MFMA flash attention (S^T trick) + circuit trig epilogue
__global__ __launch_bounds__(256,1) void k2_attn(
    const unsigned short* __restrict__ qkb, const unsigned short* __restrict__ v32t,
    const float* __restrict__ cAB, float* __restrict__ q32out){
  __shared__ __align__(16) char sm[38912];
  char* Qc  = sm;            // [64][32] bf16 swizzled (4 KB)
  char* Ks  = sm + 4096;     // [256][32] bf16 swizzled (16 KB)
  char* Vts = sm + 20480;    // [32][256+8] bf16, 528B rows (16.5 KB)
  float* OtL = (float*)sm;           // merge overlay: [4][64][36] f32
  float* mL  = (float*)(sm + 36864); // [4][64]
  float* lL  = (float*)(sm + 37888); // [4][64]

  int t = threadIdx.x, w = t>>6, l = t&63;
  int lr = l & 15, quad = l >> 4;
  int b = blockIdx.y, m0 = blockIdx.x*64;
  size_t bT = (size_t)b*2048;
  const char* qbase = (const char*)qkb + (bT + m0)*2048;       // q cols 0-511 (pre-scaled)
  const char* vbase = (const char*)v32t + (size_t)b*32*4096;

  f32x4 Ot[2][4] = {};
  float mold[4] = {-1e30f,-1e30f,-1e30f,-1e30f};
  float lsum[4] = {0.f,0.f,0.f,0.f};

  for (int step = 0; step < 8; ++step){
    int s0 = step*256;
    const char* kbase = (const char*)qkb + (bT + s0)*2048 + 1024; // k cols 512-1023
    __syncthreads();
    { // stage V^T tile [32 vcols][256 scols]
      int j = t>>3, seg = t&7;
      const uint4* vs = (const uint4*)(vbase + (size_t)j*4096 + (s0 + seg*32)*2);
      uint4* vd = (uint4*)(Vts + j*528 + seg*64);
      vd[0]=vs[0]; vd[1]=vs[1]; vd[2]=vs[2]; vd[3]=vs[3];
    }
    f32x4 acc[4][4] = {};   // S^T tile: acc[si][qj], sc=w*64+si*16+quad*4+r, qr=qj*16+lr
    for (int ec = 0; ec < 16; ++ec){
      __syncthreads();
      { int row = t>>2, sw = t&3, lc = sw ^ ((row>>1)&3);        // stage Q chunk [64][32]
        GLL16(qbase + (size_t)row*2048 + ec*64 + lc*16, Qc + w*1024); }
      #pragma unroll
      for (int rd = 0; rd < 4; ++rd){                            // stage K chunk [256][32]
        int ch = rd*256 + t, row = ch>>2, sw = ch&3, lc = sw ^ ((row>>1)&3);
        GLL16(kbase + (size_t)row*2048 + ec*64 + lc*16, Ks + rd*4096 + w*1024);
      }
      __syncthreads();
      bf16x8 af[4], bq[4];
      #pragma unroll
      for (int si = 0; si < 4; ++si){
        int row = w*64 + si*16 + lr;
        af[si] = *(const bf16x8*)(Ks + row*64 + (quad ^ ((row>>1)&3))*16);
      }
      #pragma unroll
      for (int qj = 0; qj < 4; ++qj){
        int row = qj*16 + lr;
        bq[qj] = *(const bf16x8*)(Qc + row*64 + (quad ^ ((row>>1)&3))*16);
      }
      #pragma unroll
      for (int si = 0; si < 4; ++si)
        #pragma unroll
        for (int qj = 0; qj < 4; ++qj)   // S^T = K * Q^T
          acc[si][qj] = __builtin_amdgcn_mfma_f32_16x16x32_bf16(af[si], bq[qj], acc[si][qj], 0,0,0);
    }
    // online softmax over sc (rows of S^T) + PV from registers
    bf16x4 aV[2][4];
    #pragma unroll
    for (int vt=0; vt<2; ++vt)
      #pragma unroll
      for (int si=0; si<4; ++si)
        aV[vt][si] = *(const bf16x4*)(Vts + (vt*16+lr)*528 + (w*64 + si*16 + quad*4)*2);
    #pragma unroll
    for (int qj=0; qj<4; ++qj){
      float mt = -1e30f;
      #pragma unroll
      for (int si=0; si<4; ++si)
        #pragma unroll
        for (int r=0;r<4;++r) mt = fmaxf(mt, acc[si][qj][r]);
      mt = fmaxf(mt, __shfl_xor(mt, 16));
      mt = fmaxf(mt, __shfl_xor(mt, 32));
      float mn = fmaxf(mold[qj], mt);
      float al = __expf(mold[qj] - mn);
      mold[qj] = mn;
      float rs = 0.f;
      #pragma unroll
      for (int si=0; si<4; ++si)
        #pragma unroll
        for (int r=0;r<4;++r){
          float p = __expf(acc[si][qj][r] - mn);
          acc[si][qj][r] = p; rs += p;
        }
      rs += __shfl_xor(rs, 16); rs += __shfl_xor(rs, 32);
      lsum[qj] = lsum[qj]*al + rs;
      Ot[0][qj] *= al; Ot[1][qj] *= al;
      #pragma unroll
      for (int si=0; si<4; ++si){
        bf16x4 pb;                                  // P^T in exact B-operand layout
        pb[0]=(short)f2bf(acc[si][qj][0]); pb[1]=(short)f2bf(acc[si][qj][1]);
        pb[2]=(short)f2bf(acc[si][qj][2]); pb[3]=(short)f2bf(acc[si][qj][3]);
        Ot[0][qj] = __builtin_amdgcn_mfma_f32_16x16x16bf16_1k(aV[0][si], pb, Ot[0][qj], 0,0,0);
        Ot[1][qj] = __builtin_amdgcn_mfma_f32_16x16x16bf16_1k(aV[1][si], pb, Ot[1][qj], 0,0,0);
      }
    }
  }
  // merge 4 per-wave partial streams
  __syncthreads();
  #pragma unroll
  for (int qj=0; qj<4; ++qj){
    if (quad == 0){ mL[w*64 + qj*16 + lr] = mold[qj]; lL[w*64 + qj*16 + lr] = lsum[qj]; }
    *(f32x4*)(OtL + (size_t)(w*64 + qj*16 + lr)*36 + quad*4)      = Ot[0][qj];
    *(f32x4*)(OtL + (size_t)(w*64 + qj*16 + lr)*36 + 16 + quad*4) = Ot[1][qj];
  }
  __syncthreads();
  {
    int qr = t>>2, vg = (t&3)*8;
    float M = -1e30f;
    #pragma unroll
    for (int w4=0; w4<4; ++w4) M = fmaxf(M, mL[w4*64+qr]);
    float L = 0.f; float o[8] = {};
    #pragma unroll
    for (int w4=0; w4<4; ++w4){
      float a = __expf(mL[w4*64+qr] - M);
      L += a * lL[w4*64+qr];
      const float* Op = OtL + (size_t)(w4*64+qr)*36 + vg;
      #pragma unroll
      for (int j=0;j<8;++j) o[j] += a*Op[j];
    }
    float inv = 1.f/L;
    float res[8];
    #pragma unroll
    for (int j=0;j<8;++j){
      int cc = vg+j;
      float ov = o[j]*inv;
      res[j] = cosf(ov)*cAB[cc] - sinf(ov)*cAB[32+cc];
    }
    float* dst = q32out + ((size_t)bT + m0 + qr)*32 + vg;
    *(float4*)dst     = make_float4(res[0],res[1],res[2],res[3]);
    *(float4*)(dst+4) = make_float4(res[4],res[5],res[6],res[7]);
  }
}

// ------------------- K3: attn proj (32 cols) + residual + LN1 + FFN circuit trig
__global__ __launch_bounds__(256) void k3_proj_ln(const float* __restrict__ x,
    const float* __restrict__ q32, const float* __restrict__ wo32,
    const float* __restrict__ g1, const float* __restrict__ b1,
    const float* __restrict__ cAB, float* __restrict__ x1, float* __restrict__ fbuf) {
  int tok = blockIdx.x, t = threadIdx.x;
  __shared__ float qrow[32];
  __shared__ float rs1[4], rs2[4], mv[2], shv[8];
  if (t < 32) qrow[t] = q32[(size_t)tok*32 + t];
  __syncthreads();
  float vals[2], ssum=0.f, ssq=0.f;
  #pragma unroll
  for (int u=0;u<2;u++){
    int e = t + u*256;
    float s = 0.f;
    const float4* wr = (const float4*)(wo32 + (size_t)e*32);
    #pragma unroll
    for (int c4=0;c4<8;c4++){
      float4 wv = wr[c4];
      float4 qv = *(float4*)&qrow[c4*4];
      s += wv.x*qv.x + wv.y*qv.y + wv.z*qv.z + wv.w*qv.w;
    }
    s += x[(size_t)tok*512 + e];
    vals[u]=s; ssum+=s; ssq+=s*s;
  }
  #pragma unroll
  for (int off=32; off>0; off>>=1){ ssum += __shfl_down(ssum,off); ssq += __shfl_down(ssq,off); }
  int wid = t >> 6;
  if ((t & 63) == 0){ rs1[wid]=ssum; rs2[wid]=ssq; }
  __syncthreads();
  if (t == 0){
    float a = rs1[0]+rs1[1]+rs1[2]+rs1[3];
    float b = rs2[0]+rs2[1]+rs2[2]+rs2[3];
    float mean = a * (1.f/512.f);
    float var  = b * (1.f/512.f) - mean*mean;
    mv[0]=mean; mv[1]=rsqrtf(var + 1e-5f);
  }
  __syncthreads();
  float mean=mv[0], rstd=mv[1];
  #pragma unroll
  for (int u=0;u<2;u++){
    int e = t + u*256;
    float nv = (vals[u]-mean)*rstd*g1[e] + b1[e];
    x1[(size_t)tok*512 + e] = nv;
    if (e < 8) shv[e] = nv;
  }
  __syncthreads();
  if (t < 8){
    float A = cAB[64+t], Bv = cAB[72+t];
    fbuf[(size_t)tok*8 + t] = cosf(shv[t])*A - sinf(shv[t])*Bv;
  }
}

// -------------------- K4a: Hb = bf16(relu(f @ w1^T)) for an 8192-row half
__global__ void k4a(const float* __restrict__ fbuf, const float* __restrict__ w1,
                    unsigned short* __restrict__ Hb, int row0){
  int i = blockIdx.x*256 + threadIdx.x;       // 2097152 chunks of 8 cols
  int tok = i >> 8;
  int c8 = (i & 255) * 8;
  const float* f = fbuf + (size_t)(row0 + tok)*8;
  float fv[8];
  #pragma unroll
  for (int c=0;c<8;c++) fv[c] = f[c];
  union { unsigned short h[8]; uint4 u; } o;
  #pragma unroll
  for (int j=0;j<8;j++){
    const float* wr = w1 + (size_t)(c8+j)*8;
    float s = 0.f;
    #pragma unroll
    for (int c=0;c<8;c++) s += fv[c]*wr[c];
    o.h[j] = f2bf(fmaxf(s, 0.f));
  }
  ((uint4*)Hb)[(size_t)tok*256 + (i & 255)] = o.u;
}

// --------------------------------------------- K5: out = LN(x1 + out2, g2, b2)
__global__ __launch_bounds__(256) void k5_ln2(const float* __restrict__ x1,
    const float* __restrict__ g2, const float* __restrict__ b2,
    float* __restrict__ out) {
  int tok = blockIdx.x, t = threadIdx.x;
  __shared__ float rs1[4], rs2[4], mv[2];
  float vals[2], ssum=0.f, ssq=0.f;
  #pragma unroll
  for (int u=0;u<2;u++){
    int e = t + u*256;
    float s = x1[(size_t)tok*512 + e] + out[(size_t)tok*512 + e];
    vals[u]=s; ssum+=s; ssq+=s*s;
  }
  #pragma unroll
  for (int off=32; off>0; off>>=1){ ssum += __shfl_down(ssum,off); ssq += __shfl_down(ssq,off); }
  int wid = t >> 6;
  if ((t & 63) == 0){ rs1[wid]=ssum; rs2[wid]=ssq; }
  __syncthreads();
  if (t == 0){
    float a = rs1[0]+rs1[1]+rs1[2]+rs1[3];
    float b = rs2[0]+rs2[1]+rs2[2]+rs2[3];
    float mean = a * (1.f/512.f);
    float var  = b * (1.f/512.f) - mean*mean;
    mv[0]=mean; mv[1]=rsqrtf(var + 1e-5f);
  }
  __syncthreads();
  float mean=mv[0], rstd=mv[1];
  #pragma unroll
  for (int u=0;u<2;u++){
    int e = t + u*256;
    out[(size_t)tok*512 + e] = (vals[u]-mean)*rstd*g2[e] + b2[e];
  }
}

// ---------------------------------------------------------------- launch
extern "C" void kernel_launch(void* const* d_in, const int* in_sizes, int n_in,
                              void* d_out, int out_size, void* d_ws, size_t ws_size,
                              hipStream_t stream) {
  const float* x  = (const float*)d_in[0];
  const float* wq = (const float*)d_in[1];
  const float* wk = (const float*)d_in[2];
  const float* wv = (const float*)d_in[3];
  const float* wo = (const float*)d_in[4];
  const float* hp = (const float*)d_in[5];
  const float* fp = (const float*)d_in[6];
  const float* w1 = (const float*)d_in[7];
  const float* w2 = (const float*)d_in[8];
  const float* g1 = (const float*)d_in[9];
  const float* b1 = (const float*)d_in[10];
  const float* g2 = (const float*)d_in[11];
  const float* b2 = (const float*)d_in[12];
  float* out = (float*)d_out;
  float* ws  = (float*)d_ws;

  // workspace layout (float slots), ~90.8 MB total:
  unsigned short* qkb  = (unsigned short*)(ws);             // [16384][1024] bf16 (33.5MB); reused as Hb half
  float*          x1   = ws + 8388608;                      // [16384][512] f32
  unsigned short* xb   = (unsigned short*)(ws + 16777216);  // [16384][512] bf16
  unsigned short* wqkb = (unsigned short*)(ws + 20971520);  // [1024][512] bf16 (wq scaled ; wk)
  unsigned short* w2b  = (unsigned short*)(ws + 21233664);  // [512][2048] bf16
  unsigned short* v32t = (unsigned short*)(ws + 21757952);  // [8][32][2048] bf16
  float*          q32  = ws + 22020096;                     // [16384][32] f32
  float*          fbuf = ws + 22544384;                     // [16384][8] f32
  float*          wo32 = ws + 22675456;                     // [512][32] f32
  float*          cAB  = ws + 22691840;                     // 80 consts
  unsigned short* Hb   = (unsigned short*)(ws);             // overlay (qkb dead after k2)

  k0_setup<<<17, 256, 0, stream>>>(hp, fp, wo, cAB, wo32);
  kc_cast<<<4864, 256, 0, stream>>>(x, wq, wk, w2, xb, wqkb, w2b);
  gemm_bt<512,1024,true><<<dim3(8,128), 256, 0, stream>>>(xb, wqkb, qkb, 0);
  k1_v32<<<256, 256, 0, stream>>>(x, wv, v32t);
  k2_attn<<<dim3(32,8), 256, 0, stream>>>(qkb, v32t, cAB, q32);
  k3_proj_ln<<<16384, 256, 0, stream>>>(x, q32, wo32, g1, b1, cAB, x1, fbuf);
  k4a<<<8192, 256, 0, stream>>>(fbuf, w1, Hb, 0);
  gemm_bt<2048,512,false><<<dim3(4,64), 256, 0, stream>>>(Hb, w2b, out, 0);
  k4a<<<8192, 256, 0, stream>>>(fbuf, w1, Hb, 8192);
  gemm_bt<2048,512,false><<<dim3(4,64), 256, 0, stream>>>(Hb, w2b, out, 8192);
  k5_ln2<<<16384, 256, 0, stream>>>(x1, g2, b2, out);
}

// Round 5
// 578.996 us; speedup vs baseline: 8.9341x; 1.1976x over previous
//
#include <hip/hip_runtime.h>
#include <hip/hip_bf16.h>
#include <math.h>

// B=8 T=2048 E=512 H=8 | NQ_H=4 NL=2 | NQ_F=8 FFN=2048
// Quantum circuits collapse to: qout_q = cos(x_q)*A_q - sin(x_q)*B_q (per-head/FFN consts).
// Round 5: k3_proj_ln was 147 us — 16384 blocks each re-reading 64KB wo32 from L2
// (~1 GB L2 traffic, zero reuse). Rewritten as MFMA GEMM (32 tok/block, wo32 bf16
// staged once in LDS) fused with residual+LN+trig. k0 packs wo32b bf16; k2 writes
// q32b bf16. gemm_bt / k2_attn cores byte-identical to round-3/4 verified versions.

#define B_   8
#define T_   2048
#define E_   512

typedef __attribute__((ext_vector_type(8))) short bf16x8;
typedef __attribute__((ext_vector_type(4))) short bf16x4;
typedef __attribute__((ext_vector_type(4))) float f32x4;

#define GLL16(g, l) __builtin_amdgcn_global_load_lds((const __attribute__((address_space(1))) void*)(g), (__attribute__((address_space(3))) void*)(l), 16, 0, 0)

__device__ inline unsigned short f2bf(float f){
  union { float f; unsigned u; } v; v.f = f;
  unsigned r = v.u + 0x7fff + ((v.u >> 16) & 1);   // RTNE
  return (unsigned short)(r >> 16);
}

// ------------------------------------------- K0 (parallel): circuits + wo32b pack
__global__ __launch_bounds__(256) void k0_setup(const float* __restrict__ hp,
                         const float* __restrict__ fp,
                         const float* __restrict__ wo, float* __restrict__ cAB,
                         unsigned short* __restrict__ wo32b) {
  int t = threadIdx.x, bi = blockIdx.x;
  if (bi > 0) {                      // blocks 1..16: pack wo32b bf16 (coalesced)
    int gid = (bi-1)*256 + t;        // 4096 = 512 rows x 8 groups of 4 cols
    int e = gid >> 3, c4 = gid & 7;  // wo cols c4*64 .. c4*64+3 are contiguous
    float4 v = *(const float4*)(wo + (size_t)e*512 + c4*64);
    unsigned short h[4] = { f2bf(v.x), f2bf(v.y), f2bf(v.z), f2bf(v.w) };
    *(unsigned long long*)(wo32b + (size_t)e*32 + c4*4) = *(unsigned long long*)h;
    return;
  }
  // ---- block 0: FFN 8-qubit circuit, one amplitude per thread ----
  __shared__ float fst[256], tmp[256], ra[256], rb[256];
  fst[t] = (t == 0) ? 1.f : 0.f;
  __syncthreads();
  #pragma unroll
  for (int q = 0; q < 8; ++q) {      // RY layer (params row 0)
    int str = 1 << (7-q);
    float th = 0.5f * fp[q];
    float c = cosf(th), s = sinf(th);
    float self = fst[t], part = fst[t ^ str];
    float nv = (t & str) ? (c*self + s*part) : (c*self - s*part);
    __syncthreads();
    tmp[t] = nv;
    __syncthreads();
    fst[t] = tmp[t];
    __syncthreads();
  }
  #pragma unroll
  for (int g = 0; g < 8; ++g) {      // CNOT chain + ring
    int ctrl = (g < 7) ? g : 7, tgt = (g < 7) ? g+1 : 0;
    int cs = 1 << (7-ctrl), tsr = 1 << (7-tgt);
    float nv = fst[(t & cs) ? (t ^ tsr) : t];
    __syncthreads();
    fst[t] = nv;
    __syncthreads();
  }
  #pragma unroll
  for (int q = 0; q < 8; ++q) {      // <Z_q>, <X_q>
    int str = 1 << (7-q);
    float a = fst[t]*fst[t] * ((t & str) ? -1.f : 1.f);
    float b = fst[t]*fst[t ^ str];
    ra[t] = a; rb[t] = b;
    __syncthreads();
    for (int off = 128; off > 0; off >>= 1){
      if (t < off){ ra[t] += ra[t+off]; rb[t] += rb[t+off]; }
      __syncthreads();
    }
    if (t == 0){ cAB[64+q] = ra[0]; cAB[72+q] = rb[0]; }
    __syncthreads();
  }
  // ---- per-head 4-qubit circuits: 8 parallel threads, 16 amps in registers ----
  if (t < 8) {
    float st[16];
    #pragma unroll
    for (int i=0;i<16;i++) st[i]=0.f;
    st[0]=1.f;
    for (int l=0;l<2;l++){
      for (int q=0;q<4;q++){
        float th = 0.5f*hp[t*8 + l*4 + q];
        float c = cosf(th), s = sinf(th);
        int str = 1<<(3-q);
        for (int i=0;i<16;i++) if (!(i & str)) {
          float s0=st[i], s1=st[i|str];
          st[i]     = c*s0 - s*s1;
          st[i|str] = s*s0 + c*s1;
        }
      }
      for (int q=0;q<4;q++){
        int ctrl = (q<3)? q : 3, tgt = (q<3)? q+1 : 0;
        int cs = 1<<(3-ctrl), tsr = 1<<(3-tgt);
        for (int i=0;i<16;i++) if ((i&cs) && !(i&tsr)) {
          float tt = st[i]; st[i]=st[i|tsr]; st[i|tsr]=tt;
        }
      }
    }
    for (int q=0;q<4;q++){
      int str = 1<<(3-q);
      float A=0.f, Bv=0.f;
      for (int i=0;i<16;i++){
        A  += st[i]*st[i] * ((i&str)? -1.f : 1.f);
        Bv += st[i]*st[i^str];
      }
      cAB[t*4+q]    = A;
      cAB[32+t*4+q] = Bv;
    }
  }
}

// -------------------------------------- merged casts to bf16 (xb | wqkb,w2b)
__global__ __launch_bounds__(256) void kc_cast(const float* __restrict__ x,
                     const float* __restrict__ wq, const float* __restrict__ wk,
                     const float* __restrict__ w2, unsigned short* __restrict__ xb,
                     unsigned short* __restrict__ wqkb, unsigned short* __restrict__ w2b){
  int bi = blockIdx.x;
  if (bi < 4096) {                                 // x -> xb: 1048576 chunks of 8
    int i = bi*256 + threadIdx.x;
    const float4* p = (const float4*)x + (size_t)i*2;
    float4 a = p[0], b = p[1];
    union { unsigned short h[8]; uint4 u; } o;
    o.h[0]=f2bf(a.x); o.h[1]=f2bf(a.y); o.h[2]=f2bf(a.z); o.h[3]=f2bf(a.w);
    o.h[4]=f2bf(b.x); o.h[5]=f2bf(b.y); o.h[6]=f2bf(b.z); o.h[7]=f2bf(b.w);
    ((uint4*)xb)[i] = o.u;
    return;
  }
  int i = (bi-4096)*256 + threadIdx.x;             // 196608 chunks of 8
  const float* src; unsigned short* dst; float s = 1.f;
  if (i < 65536){
    int row = i >> 6, c8 = (i & 63)*8;
    if (row < 512){ src = wq + (size_t)row*512 + c8; s = 0.044194173824159216f; } // fold 1/sqrt(E)
    else          { src = wk + (size_t)(row-512)*512 + c8; }
    dst = wqkb + (size_t)row*512 + c8;
  } else {
    int j = i - 65536;
    src = w2 + (size_t)j*8; dst = w2b + (size_t)j*8;
  }
  float4 a = *(const float4*)src, b = *(const float4*)(src+4);
  union { unsigned short h[8]; uint4 u; } o;
  o.h[0]=f2bf(a.x*s); o.h[1]=f2bf(a.y*s); o.h[2]=f2bf(a.z*s); o.h[3]=f2bf(a.w*s);
  o.h[4]=f2bf(b.x*s); o.h[5]=f2bf(b.y*s); o.h[6]=f2bf(b.z*s); o.h[7]=f2bf(b.w*s);
  *(uint4*)dst = o.u;
}

// -------------------------------- m97-style MFMA GEMM: C = A (MxK) * Bw^T (NxK)
template<int K, int LDC, bool OUTBF>
__global__ __launch_bounds__(256,2) void gemm_bt(
    const unsigned short* __restrict__ A, const unsigned short* __restrict__ Bw,
    void* __restrict__ C, int m_base){
  __shared__ __align__(16) char sm[16384];
  char* As = sm; char* Bs = sm + 8192;             // [128][32] bf16, 64B rows, xor-swizzled
  int t = threadIdx.x, w = t>>6, l = t&63;
  int lr = l&15, quad = l>>4;
  int m0 = blockIdx.y*128, n0 = blockIdx.x*128;
  int wr = (w>>1)*64, wc = (w&1)*64;
  f32x4 acc[4][4] = {};
  for (int k0 = 0; k0 < K; k0 += 32){
    __syncthreads();
    #pragma unroll
    for (int c = 0; c < 2; ++c){
      int ch = c*256 + t, row = ch>>2, sw = ch&3, lc = sw ^ ((row>>1)&3);
      GLL16(A  + (size_t)(m0+row)*K + k0 + lc*8, As + c*4096 + w*1024);
      GLL16(Bw + (size_t)(n0+row)*K + k0 + lc*8, Bs + c*4096 + w*1024);
    }
    __syncthreads();
    bf16x8 af[4], bg[4];
    #pragma unroll
    for (int i=0;i<4;++i){
      int ra = wr + i*16 + lr;
      af[i] = *(const bf16x8*)(As + ra*64 + (quad ^ ((ra>>1)&3))*16);
      int rb = wc + i*16 + lr;
      bg[i] = *(const bf16x8*)(Bs + rb*64 + (quad ^ ((rb>>1)&3))*16);
    }
    #pragma unroll
    for (int i=0;i<4;++i)
      #pragma unroll
      for (int j=0;j<4;++j)
        acc[i][j] = __builtin_amdgcn_mfma_f32_16x16x32_bf16(af[i], bg[j], acc[i][j], 0,0,0);
  }
  #pragma unroll
  for (int i=0;i<4;++i)
    #pragma unroll
    for (int j=0;j<4;++j)
      #pragma unroll
      for (int r=0;r<4;++r){
        size_t row = (size_t)(m_base + m0 + wr + i*16 + quad*4 + r);
        int col = n0 + wc + j*16 + lr;
        if constexpr (OUTBF) ((unsigned short*)C)[row*LDC + col] = f2bf(acc[i][j][r]);
        else                 ((float*)C)[row*LDC + col] = acc[i][j][r];
      }
}

// ------------------------------------- K1v: v32t[b][c][s] = bf16(x @ wv[used]^T)
__global__ __launch_bounds__(256) void k1_v32(const float* __restrict__ x,
    const float* __restrict__ wv, unsigned short* __restrict__ v32t) {
  int m0 = blockIdx.x * 64;
  __shared__ float Xs[64][36];
  __shared__ float Ws[32][36];
  int t = threadIdx.x;
  int m = t >> 2, c0 = (t & 3) * 8;
  float acc[8] = {};
  for (int k0 = 0; k0 < 512; k0 += 32) {
    #pragma unroll
    for (int u=0; u<2; u++){
      int idx = t + u*256;
      int r = idx >> 3, c4 = (idx & 7) * 4;
      *(float4*)&Xs[r][c4] = *(const float4*)(x + (size_t)(m0+r)*512 + k0 + c4);
    }
    { int r = t >> 3, c4 = (t & 7) * 4;
      int wrow = (r>>2)*64 + (r&3);
      *(float4*)&Ws[r][c4] = *(const float4*)(wv + (size_t)wrow*512 + k0 + c4);
    }
    __syncthreads();
    #pragma unroll
    for (int kk=0; kk<32; kk++){
      float xv = Xs[m][kk];
      #pragma unroll
      for (int j=0;j<8;j++) acc[j] += xv * Ws[c0+j][kk];
    }
    __syncthreads();
  }
  int tok = m0 + m, bb = tok >> 11, s = tok & 2047;
  #pragma unroll
  for (int j=0;j<8;j++)
    v32t[((size_t)(bb*32 + c0 + j))*2048 + s] = f2bf(acc[j]);
}

// -------------------- K2: MFMA flash attention (S^T trick) + circuit trig epilogue
__global__ __launch_bounds__(256,1) void k2_attn(
    const unsigned short* __restrict__ qkb, const unsigned short* __restrict__ v32t,
    const float* __restrict__ cAB, unsigned short* __restrict__ q32b){
  __shared__ __align__(16) char sm[38912];
  char* Qc  = sm;            // [64][32] bf16 swizzled (4 KB)
  char* Ks  = sm + 4096;     // [256][32] bf16 swizzled (16 KB)
  char* Vts = sm + 20480;    // [32][256+8] bf16, 528B rows (16.5 KB)
  float* OtL = (float*)sm;           // merge overlay: [4][64][36] f32
  float* mL  = (float*)(sm + 36864); // [4][64]
  float* lL  = (float*)(sm + 37888); // [4][64]

  int t = threadIdx.x, w = t>>6, l = t&63;
  int lr = l & 15, quad = l >> 4;
  int b = blockIdx.y, m0 = blockIdx.x*64;
  size_t bT = (size_t)b*2048;
  const char* qbase = (const char*)qkb + (bT + m0)*2048;       // q cols 0-511 (pre-scaled)
  const char* vbase = (const char*)v32t + (size_t)b*32*4096;

  f32x4 Ot[2][4] = {};
  float mold[4] = {-1e30f,-1e30f,-1e30f,-1e30f};
  float lsum[4] = {0.f,0.f,0.f,0.f};

  for (int step = 0; step < 8; ++step){
    int s0 = step*256;
    const char* kbase = (const char*)qkb + (bT + s0)*2048 + 1024; // k cols 512-1023
    __syncthreads();
    { // stage V^T tile [32 vcols][256 scols]
      int j = t>>3, seg = t&7;
      const uint4* vs = (const uint4*)(vbase + (size_t)j*4096 + (s0 + seg*32)*2);
      uint4* vd = (uint4*)(Vts + j*528 + seg*64);
      vd[0]=vs[0]; vd[1]=vs[1]; vd[2]=vs[2]; vd[3]=vs[3];
    }
    f32x4 acc[4][4] = {};   // S^T tile: acc[si][qj], sc=w*64+si*16+quad*4+r, qr=qj*16+lr
    for (int ec = 0; ec < 16; ++ec){
      __syncthreads();
      { int row = t>>2, sw = t&3, lc = sw ^ ((row>>1)&3);        // stage Q chunk [64][32]
        GLL16(qbase + (size_t)row*2048 + ec*64 + lc*16, Qc + w*1024); }
      #pragma unroll
      for (int rd = 0; rd < 4; ++rd){                            // stage K chunk [256][32]
        int ch = rd*256 + t, row = ch>>2, sw = ch&3, lc = sw ^ ((row>>1)&3);
        GLL16(kbase + (size_t)row*2048 + ec*64 + lc*16, Ks + rd*4096 + w*1024);
      }
      __syncthreads();
      bf16x8 af[4], bq[4];
      #pragma unroll
      for (int si = 0; si < 4; ++si){
        int row = w*64 + si*16 + lr;
        af[si] = *(const bf16x8*)(Ks + row*64 + (quad ^ ((row>>1)&3))*16);
      }
      #pragma unroll
      for (int qj = 0; qj < 4; ++qj){
        int row = qj*16 + lr;
        bq[qj] = *(const bf16x8*)(Qc + row*64 + (quad ^ ((row>>1)&3))*16);
      }
      #pragma unroll
      for (int si = 0; si < 4; ++si)
        #pragma unroll
        for (int qj = 0; qj < 4; ++qj)   // S^T = K * Q^T
          acc[si][qj] = __builtin_amdgcn_mfma_f32_16x16x32_bf16(af[si], bq[qj], acc[si][qj], 0,0,0);
    }
    // online softmax over sc (rows of S^T) + PV from registers
    bf16x4 aV[2][4];
    #pragma unroll
    for (int vt=0; vt<2; ++vt)
      #pragma unroll
      for (int si=0; si<4; ++si)
        aV[vt][si] = *(const bf16x4*)(Vts + (vt*16+lr)*528 + (w*64 + si*16 + quad*4)*2);
    #pragma unroll
    for (int qj=0; qj<4; ++qj){
      float mt = -1e30f;
      #pragma unroll
      for (int si=0; si<4; ++si)
        #pragma unroll
        for (int r=0;r<4;++r) mt = fmaxf(mt, acc[si][qj][r]);
      mt = fmaxf(mt, __shfl_xor(mt, 16));
      mt = fmaxf(mt, __shfl_xor(mt, 32));
      float mn = fmaxf(mold[qj], mt);
      float al = __expf(mold[qj] - mn);
      mold[qj] = mn;
      float rs = 0.f;
      #pragma unroll
      for (int si=0; si<4; ++si)
        #pragma unroll
        for (int r=0;r<4;++r){
          float p = __expf(acc[si][qj][r] - mn);
          acc[si][qj][r] = p; rs += p;
        }
      rs += __shfl_xor(rs, 16); rs += __shfl_xor(rs, 32);
      lsum[qj] = lsum[qj]*al + rs;
      Ot[0][qj] *= al; Ot[1][qj] *= al;
      #pragma unroll
      for (int si=0; si<4; ++si){
        bf16x4 pb;                                  // P^T in exact B-operand layout
        pb[0]=(short)f2bf(acc[si][qj][0]); pb[1]=(short)f2bf(acc[si][qj][1]);
        pb[2]=(short)f2bf(acc[si][qj][2]); pb[3]=(short)f2bf(acc[si][qj][3]);
        Ot[0][qj] = __builtin_amdgcn_mfma_f32_16x16x16bf16_1k(aV[0][si], pb, Ot[0][qj], 0,0,0);
        Ot[1][qj] = __builtin_amdgcn_mfma_f32_16x16x16bf16_1k(aV[1][si], pb, Ot[1][qj], 0,0,0);
      }
    }
  }
  // merge 4 per-wave partial streams
  __syncthreads();
  #pragma unroll
  for (int qj=0; qj<4; ++qj){
    if (quad == 0){ mL[w*64 + qj*16 + lr] = mold[qj]; lL[w*64 + qj*16 + lr] = lsum[qj]; }
    *(f32x4*)(OtL + (size_t)(w*64 + qj*16 + lr)*36 + quad*4)      = Ot[0][qj];
    *(f32x4*)(OtL + (size_t)(w*64 + qj*16 + lr)*36 + 16 + quad*4) = Ot[1][qj];
  }
  __syncthreads();
  {
    int qr = t>>2, vg = (t&3)*8;
    float M = -1e30f;
    #pragma unroll
    for (int w4=0; w4<4; ++w4) M = fmaxf(M, mL[w4*64+qr]);
    float L = 0.f; float o[8] = {};
    #pragma unroll
    for (int w4=0; w4<4; ++w4){
      float a = __expf(mL[w4*64+qr] - M);
      L += a * lL[w4*64+qr];
      const float* Op = OtL + (size_t)(w4*64+qr)*36 + vg;
      #pragma unroll
      for (int j=0;j<8;++j) o[j] += a*Op[j];
    }
    float inv = 1.f/L;
    union { unsigned short h[8]; uint4 u; } res;
    #pragma unroll
    for (int j=0;j<8;++j){
      int cc = vg+j;
      float ov = o[j]*inv;
      res.h[j] = f2bf(cosf(ov)*cAB[cc] - sinf(ov)*cAB[32+cc]);
    }
    *(uint4*)(q32b + ((size_t)bT + m0 + qr)*32 + vg) = res.u;
  }
}

// ---- K3 (MFMA): x1 = LN(x + q32b@wo32b^T, g1,b1); fbuf = trig(x1[:, :8])
__global__ __launch_bounds__(256) void k3_proj_ln(const float* __restrict__ x,
    const unsigned short* __restrict__ q32b, const unsigned short* __restrict__ wo32b,
    const float* __restrict__ g1, const float* __restrict__ b1,
    const float* __restrict__ cAB, float* __restrict__ x1, float* __restrict__ fbuf) {
  __shared__ __align__(16) char sm3[36224];
  char* Ws = sm3;                          // [512][32] bf16 swizzled, 32 KB
  char* Qs = sm3 + 32768;                  // [32][32] bf16 swizzled, 2 KB
  float* red1 = (float*)(sm3 + 34816);     // [4][32]
  float* red2 = (float*)(sm3 + 35328);     // [4][32]
  float* mm   = (float*)(sm3 + 35840);     // [32]
  float* rr   = (float*)(sm3 + 35968);     // [32]
  int t = threadIdx.x, w = t>>6, l = t&63, lr = l&15, quad = l>>4;
  int tok0 = blockIdx.x * 32;
  #pragma unroll
  for (int i=0;i<8;++i){                   // stage wo32b: 2048 uint4
    int g = t + i*256, row = g>>2, ch = g&3;
    uint4 v = ((const uint4*)wo32b)[g];
    *(uint4*)(Ws + row*64 + (ch ^ ((row>>1)&3))*16) = v;
  }
  if (t < 128){                            // stage q tile: 128 uint4
    int row = t>>2, ch = t&3;
    uint4 v = ((const uint4*)(q32b + (size_t)tok0*32))[t];
    *(uint4*)(Qs + row*64 + (ch ^ ((row>>1)&3))*16) = v;
  }
  __syncthreads();
  bf16x8 af[2], bf[8];
  #pragma unroll
  for (int i=0;i<2;++i){
    int m = i*16 + lr;
    af[i] = *(const bf16x8*)(Qs + m*64 + (quad ^ ((m>>1)&3))*16);
  }
  #pragma unroll
  for (int j=0;j<8;++j){
    int n = w*128 + j*16 + lr;
    bf[j] = *(const bf16x8*)(Ws + n*64 + (quad ^ ((n>>1)&3))*16);
  }
  f32x4 acc[2][8];
  #pragma unroll
  for (int i=0;i<2;++i)
    #pragma unroll
    for (int j=0;j<8;++j){
      f32x4 z = {0.f,0.f,0.f,0.f};
      acc[i][j] = __builtin_amdgcn_mfma_f32_16x16x32_bf16(af[i], bf[j], z, 0,0,0);
    }
  // residual add + row-sum accumulation
  float s1[2][4] = {}, s2[2][4] = {};
  #pragma unroll
  for (int i=0;i<2;++i)
    #pragma unroll
    for (int r=0;r<4;++r){
      int m = i*16 + quad*4 + r;
      const float* xrow = x + (size_t)(tok0+m)*512 + w*128 + lr;
      #pragma unroll
      for (int j=0;j<8;++j){
        float v = acc[i][j][r] + xrow[j*16];
        acc[i][j][r] = v;
        s1[i][r] += v; s2[i][r] += v*v;
      }
    }
  #pragma unroll
  for (int off=1; off<16; off<<=1){
    #pragma unroll
    for (int i=0;i<2;++i)
      #pragma unroll
      for (int r=0;r<4;++r){
        s1[i][r] += __shfl_xor(s1[i][r], off);
        s2[i][r] += __shfl_xor(s2[i][r], off);
      }
  }
  if (lr == 0){
    #pragma unroll
    for (int i=0;i<2;++i)
      #pragma unroll
      for (int r=0;r<4;++r){
        int m = i*16 + quad*4 + r;
        red1[w*32 + m] = s1[i][r];
        red2[w*32 + m] = s2[i][r];
      }
  }
  __syncthreads();
  if (t < 32){
    float a = red1[t] + red1[32+t] + red1[64+t] + red1[96+t];
    float bb = red2[t] + red2[32+t] + red2[64+t] + red2[96+t];
    float mean = a * (1.f/512.f);
    float var  = bb * (1.f/512.f) - mean*mean;
    mm[t] = mean; rr[t] = rsqrtf(var + 1e-5f);
  }
  __syncthreads();
  float g1v[8], b1v[8];
  #pragma unroll
  for (int j=0;j<8;++j){
    int n = w*128 + j*16 + lr;
    g1v[j] = g1[n]; b1v[j] = b1[n];
  }
  #pragma unroll
  for (int i=0;i<2;++i)
    #pragma unroll
    for (int r=0;r<4;++r){
      int m = i*16 + quad*4 + r;
      float mean = mm[m], rstd = rr[m];
      float* orow = x1 + (size_t)(tok0+m)*512 + w*128 + lr;
      #pragma unroll
      for (int j=0;j<8;++j){
        float nv = (acc[i][j][r]-mean)*rstd*g1v[j] + b1v[j];
        orow[j*16] = nv;
        if (w == 0 && j == 0 && lr < 8)
          fbuf[(size_t)(tok0+m)*8 + lr] = cosf(nv)*cAB[64+lr] - sinf(nv)*cAB[72+lr];
      }
    }
}

// -------------------- K4a: Hb = bf16(relu(f @ w1^T)) for an 8192-row half
__global__ void k4a(const float* __restrict__ fbuf, const float* __restrict__ w1,
                    unsigned short* __restrict__ Hb, int row0){
  int i = blockIdx.x*256 + threadIdx.x;       // 2097152 chunks of 8 cols
  int tok = i >> 8;
  int c8 = (i & 255) * 8;
  const float* f = fbuf + (size_t)(row0 + tok)*8;
  float fv[8];
  #pragma unroll
  for (int c=0;c<8;c++) fv[c] = f[c];
  union { unsigned short h[8]; uint4 u; } o;
  #pragma unroll
  for (int j=0;j<8;j++){
    const float* wr = w1 + (size_t)(c8+j)*8;
    float s = 0.f;
    #pragma unroll
    for (int c=0;c<8;c++) s += fv[c]*wr[c];
    o.h[j] = f2bf(fmaxf(s, 0.f));
  }
  ((uint4*)Hb)[(size_t)tok*256 + (i & 255)] = o.u;
}

// --------------------------------------------- K5: out = LN(x1 + out2, g2, b2)
__global__ __launch_bounds__(256) void k5_ln2(const float* __restrict__ x1,
    const float* __restrict__ g2, const float* __restrict__ b2,
    float* __restrict__ out) {
  int tok = blockIdx.x, t = threadIdx.x;
  __shared__ float rs1[4], rs2[4], mv[2];
  float vals[2], ssum=0.f, ssq=0.f;
  #pragma unroll
  for (int u=0;u<2;u++){
    int e = t + u*256;
    float s = x1[(size_t)tok*512 + e] + out[(size_t)tok*512 + e];
    vals[u]=s; ssum+=s; ssq+=s*s;
  }
  #pragma unroll
  for (int off=32; off>0; off>>=1){ ssum += __shfl_down(ssum,off); ssq += __shfl_down(ssq,off); }
  int wid = t >> 6;
  if ((t & 63) == 0){ rs1[wid]=ssum; rs2[wid]=ssq; }
  __syncthreads();
  if (t == 0){
    float a = rs1[0]+rs1[1]+rs1[2]+rs1[3];
    float b = rs2[0]+rs2[1]+rs2[2]+rs2[3];
    float mean = a * (1.f/512.f);
    float var  = b * (1.f/512.f) - mean*mean;
    mv[0]=mean; mv[1]=rsqrtf(var + 1e-5f);
  }
  __syncthreads();
  float mean=mv[0], rstd=mv[1];
  #pragma unroll
  for (int u=0;u<2;u++){
    int e = t + u*256;
    out[(size_t)tok*512 + e] = (vals[u]-mean)*rstd*g2[e] + b2[e];
  }
}

// ---------------------------------------------------------------- launch
extern "C" void kernel_launch(void* const* d_in, const int* in_sizes, int n_in,
                              void* d_out, int out_size, void* d_ws, size_t ws_size,
                              hipStream_t stream) {
  const float* x  = (const float*)d_in[0];
  const float* wq = (const float*)d_in[1];
  const float* wk = (const float*)d_in[2];
  const float* wv = (const float*)d_in[3];
  const float* wo = (const float*)d_in[4];
  const float* hp = (const float*)d_in[5];
  const float* fp = (const float*)d_in[6];
  const float* w1 = (const float*)d_in[7];
  const float* w2 = (const float*)d_in[8];
  const float* g1 = (const float*)d_in[9];
  const float* b1 = (const float*)d_in[10];
  const float* g2 = (const float*)d_in[11];
  const float* b2 = (const float*)d_in[12];
  float* out = (float*)d_out;
  float* ws  = (float*)d_ws;

  // workspace layout (float slots), ~90.8 MB total:
  unsigned short* qkb  = (unsigned short*)(ws);             // [16384][1024] bf16 (33.5MB); reused as Hb half
  float*          x1   = ws + 8388608;                      // [16384][512] f32
  unsigned short* xb   = (unsigned short*)(ws + 16777216);  // [16384][512] bf16
  unsigned short* wqkb = (unsigned short*)(ws + 20971520);  // [1024][512] bf16 (wq scaled ; wk)
  unsigned short* w2b  = (unsigned short*)(ws + 21233664);  // [512][2048] bf16
  unsigned short* v32t = (unsigned short*)(ws + 21757952);  // [8][32][2048] bf16
  unsigned short* q32b = (unsigned short*)(ws + 22020096);  // [16384][32] bf16
  float*          fbuf = ws + 22544384;                     // [16384][8] f32
  unsigned short* wo32b= (unsigned short*)(ws + 22675456);  // [512][32] bf16
  float*          cAB  = ws + 22691840;                     // 80 consts
  unsigned short* Hb   = (unsigned short*)(ws);             // overlay (qkb dead after k2)

  k0_setup<<<17, 256, 0, stream>>>(hp, fp, wo, cAB, wo32b);
  kc_cast<<<4864, 256, 0, stream>>>(x, wq, wk, w2, xb, wqkb, w2b);
  gemm_bt<512,1024,true><<<dim3(8,128), 256, 0, stream>>>(xb, wqkb, qkb, 0);
  k1_v32<<<256, 256, 0, stream>>>(x, wv, v32t);
  k2_attn<<<dim3(32,8), 256, 0, stream>>>(qkb, v32t, cAB, q32b);
  k3_proj_ln<<<512, 256, 0, stream>>>(x, q32b, wo32b, g1, b1, cAB, x1, fbuf);
  k4a<<<8192, 256, 0, stream>>>(fbuf, w1, Hb, 0);
  gemm_bt<2048,512,false><<<dim3(4,64), 256, 0, stream>>>(Hb, w2b, out, 0);
  k4a<<<8192, 256, 0, stream>>>(fbuf, w1, Hb, 8192);
  gemm_bt<2048,512,false><<<dim3(4,64), 256, 0, stream>>>(Hb, w2b, out, 8192);
  k5_ln2<<<16384, 256, 0, stream>>>(x1, g2, b2, out);
}

// Round 6
// 558.989 us; speedup vs baseline: 9.2539x; 1.0358x over previous
//
#include <hip/hip_runtime.h>
#include <hip/hip_bf16.h>
#include <math.h>

// B=8 T=2048 E=512 H=8 | NQ_H=4 NL=2 | NQ_F=8 FFN=2048
// Quantum circuits collapse to: qout_q = cos(x_q)*A_q - sin(x_q)*B_q (per-head/FFN consts).
// Round 6: k2 was 115 us, FETCH 134MB = redundant Q re-stage (8 steps x 16 ec) missing
// L2 because blocks of one batch scatter across XCDs. Fixes: (1) XCD-aware remap in k2
// (b = lin&7 -> one batch per XCD, K+Q+V of that batch fit the 4MB L2), (2) BK=64
// (64 barrier-drains instead of 128; LDS 56.5KB), (3) XCD-aware m/n swizzle in gemm_bt
// (A-tile re-reads become intra-XCD L2 hits). Softmax/PV/merge logic unchanged.

#define B_   8
#define T_   2048
#define E_   512

typedef __attribute__((ext_vector_type(8))) short bf16x8;
typedef __attribute__((ext_vector_type(4))) short bf16x4;
typedef __attribute__((ext_vector_type(4))) float f32x4;

#define GLL16(g, l) __builtin_amdgcn_global_load_lds((const __attribute__((address_space(1))) void*)(g), (__attribute__((address_space(3))) void*)(l), 16, 0, 0)

__device__ inline unsigned short f2bf(float f){
  union { float f; unsigned u; } v; v.f = f;
  unsigned r = v.u + 0x7fff + ((v.u >> 16) & 1);   // RTNE
  return (unsigned short)(r >> 16);
}

// ------------------------------------------- K0 (parallel): circuits + wo32b pack
__global__ __launch_bounds__(256) void k0_setup(const float* __restrict__ hp,
                         const float* __restrict__ fp,
                         const float* __restrict__ wo, float* __restrict__ cAB,
                         unsigned short* __restrict__ wo32b) {
  int t = threadIdx.x, bi = blockIdx.x;
  if (bi > 0) {                      // blocks 1..16: pack wo32b bf16 (coalesced)
    int gid = (bi-1)*256 + t;        // 4096 = 512 rows x 8 groups of 4 cols
    int e = gid >> 3, c4 = gid & 7;  // wo cols c4*64 .. c4*64+3 are contiguous
    float4 v = *(const float4*)(wo + (size_t)e*512 + c4*64);
    unsigned short h[4] = { f2bf(v.x), f2bf(v.y), f2bf(v.z), f2bf(v.w) };
    *(unsigned long long*)(wo32b + (size_t)e*32 + c4*4) = *(unsigned long long*)h;
    return;
  }
  // ---- block 0: FFN 8-qubit circuit, one amplitude per thread ----
  __shared__ float fst[256], tmp[256], ra[256], rb[256];
  fst[t] = (t == 0) ? 1.f : 0.f;
  __syncthreads();
  #pragma unroll
  for (int q = 0; q < 8; ++q) {      // RY layer (params row 0)
    int str = 1 << (7-q);
    float th = 0.5f * fp[q];
    float c = cosf(th), s = sinf(th);
    float self = fst[t], part = fst[t ^ str];
    float nv = (t & str) ? (c*self + s*part) : (c*self - s*part);
    __syncthreads();
    tmp[t] = nv;
    __syncthreads();
    fst[t] = tmp[t];
    __syncthreads();
  }
  #pragma unroll
  for (int g = 0; g < 8; ++g) {      // CNOT chain + ring
    int ctrl = (g < 7) ? g : 7, tgt = (g < 7) ? g+1 : 0;
    int cs = 1 << (7-ctrl), tsr = 1 << (7-tgt);
    float nv = fst[(t & cs) ? (t ^ tsr) : t];
    __syncthreads();
    fst[t] = nv;
    __syncthreads();
  }
  #pragma unroll
  for (int q = 0; q < 8; ++q) {      // <Z_q>, <X_q>
    int str = 1 << (7-q);
    float a = fst[t]*fst[t] * ((t & str) ? -1.f : 1.f);
    float b = fst[t]*fst[t ^ str];
    ra[t] = a; rb[t] = b;
    __syncthreads();
    for (int off = 128; off > 0; off >>= 1){
      if (t < off){ ra[t] += ra[t+off]; rb[t] += rb[t+off]; }
      __syncthreads();
    }
    if (t == 0){ cAB[64+q] = ra[0]; cAB[72+q] = rb[0]; }
    __syncthreads();
  }
  // ---- per-head 4-qubit circuits: 8 parallel threads, 16 amps in registers ----
  if (t < 8) {
    float st[16];
    #pragma unroll
    for (int i=0;i<16;i++) st[i]=0.f;
    st[0]=1.f;
    for (int l=0;l<2;l++){
      for (int q=0;q<4;q++){
        float th = 0.5f*hp[t*8 + l*4 + q];
        float c = cosf(th), s = sinf(th);
        int str = 1<<(3-q);
        for (int i=0;i<16;i++) if (!(i & str)) {
          float s0=st[i], s1=st[i|str];
          st[i]     = c*s0 - s*s1;
          st[i|str] = s*s0 + c*s1;
        }
      }
      for (int q=0;q<4;q++){
        int ctrl = (q<3)? q : 3, tgt = (q<3)? q+1 : 0;
        int cs = 1<<(3-ctrl), tsr = 1<<(3-tgt);
        for (int i=0;i<16;i++) if ((i&cs) && !(i&tsr)) {
          float tt = st[i]; st[i]=st[i|tsr]; st[i|tsr]=tt;
        }
      }
    }
    for (int q=0;q<4;q++){
      int str = 1<<(3-q);
      float A=0.f, Bv=0.f;
      for (int i=0;i<16;i++){
        A  += st[i]*st[i] * ((i&str)? -1.f : 1.f);
        Bv += st[i]*st[i^str];
      }
      cAB[t*4+q]    = A;
      cAB[32+t*4+q] = Bv;
    }
  }
}

// -------------------------------------- merged casts to bf16 (xb | wqkb,w2b)
__global__ __launch_bounds__(256) void kc_cast(const float* __restrict__ x,
                     const float* __restrict__ wq, const float* __restrict__ wk,
                     const float* __restrict__ w2, unsigned short* __restrict__ xb,
                     unsigned short* __restrict__ wqkb, unsigned short* __restrict__ w2b){
  int bi = blockIdx.x;
  if (bi < 4096) {                                 // x -> xb: 1048576 chunks of 8
    int i = bi*256 + threadIdx.x;
    const float4* p = (const float4*)x + (size_t)i*2;
    float4 a = p[0], b = p[1];
    union { unsigned short h[8]; uint4 u; } o;
    o.h[0]=f2bf(a.x); o.h[1]=f2bf(a.y); o.h[2]=f2bf(a.z); o.h[3]=f2bf(a.w);
    o.h[4]=f2bf(b.x); o.h[5]=f2bf(b.y); o.h[6]=f2bf(b.z); o.h[7]=f2bf(b.w);
    ((uint4*)xb)[i] = o.u;
    return;
  }
  int i = (bi-4096)*256 + threadIdx.x;             // 196608 chunks of 8
  const float* src; unsigned short* dst; float s = 1.f;
  if (i < 65536){
    int row = i >> 6, c8 = (i & 63)*8;
    if (row < 512){ src = wq + (size_t)row*512 + c8; s = 0.044194173824159216f; } // fold 1/sqrt(E)
    else          { src = wk + (size_t)(row-512)*512 + c8; }
    dst = wqkb + (size_t)row*512 + c8;
  } else {
    int j = i - 65536;
    src = w2 + (size_t)j*8; dst = w2b + (size_t)j*8;
  }
  float4 a = *(const float4*)src, b = *(const float4*)(src+4);
  union { unsigned short h[8]; uint4 u; } o;
  o.h[0]=f2bf(a.x*s); o.h[1]=f2bf(a.y*s); o.h[2]=f2bf(a.z*s); o.h[3]=f2bf(a.w*s);
  o.h[4]=f2bf(b.x*s); o.h[5]=f2bf(b.y*s); o.h[6]=f2bf(b.z*s); o.h[7]=f2bf(b.w*s);
  *(uint4*)dst = o.u;
}

// ------------- m97-style MFMA GEMM: C = A (MxK) * Bw^T (NxK), XCD-aware swizzle
// 1-D grid of GX*GM blocks; same-XCD blocks (lin%8) share A m-tiles via L2.
template<int K, int LDC, bool OUTBF, int GX, int GM>
__global__ __launch_bounds__(256,2) void gemm_bt(
    const unsigned short* __restrict__ A, const unsigned short* __restrict__ Bw,
    void* __restrict__ C, int m_base){
  __shared__ __align__(16) char sm[16384];
  char* As = sm; char* Bs = sm + 8192;             // [128][32] bf16, 64B rows, xor-swizzled
  int t = threadIdx.x, w = t>>6, l = t&63;
  int lr = l&15, quad = l>>4;
  int lin = blockIdx.x;
  int n0 = ((lin >> 3) % GX) * 128;
  int m0 = ((lin & 7) * (GM/8) + lin / (8*GX)) * 128;
  int wr = (w>>1)*64, wc = (w&1)*64;
  f32x4 acc[4][4] = {};
  for (int k0 = 0; k0 < K; k0 += 32){
    __syncthreads();
    #pragma unroll
    for (int c = 0; c < 2; ++c){
      int ch = c*256 + t, row = ch>>2, sw = ch&3, lc = sw ^ ((row>>1)&3);
      GLL16(A  + (size_t)(m0+row)*K + k0 + lc*8, As + c*4096 + w*1024);
      GLL16(Bw + (size_t)(n0+row)*K + k0 + lc*8, Bs + c*4096 + w*1024);
    }
    __syncthreads();
    bf16x8 af[4], bg[4];
    #pragma unroll
    for (int i=0;i<4;++i){
      int ra = wr + i*16 + lr;
      af[i] = *(const bf16x8*)(As + ra*64 + (quad ^ ((ra>>1)&3))*16);
      int rb = wc + i*16 + lr;
      bg[i] = *(const bf16x8*)(Bs + rb*64 + (quad ^ ((rb>>1)&3))*16);
    }
    #pragma unroll
    for (int i=0;i<4;++i)
      #pragma unroll
      for (int j=0;j<4;++j)
        acc[i][j] = __builtin_amdgcn_mfma_f32_16x16x32_bf16(af[i], bg[j], acc[i][j], 0,0,0);
  }
  #pragma unroll
  for (int i=0;i<4;++i)
    #pragma unroll
    for (int j=0;j<4;++j)
      #pragma unroll
      for (int r=0;r<4;++r){
        size_t row = (size_t)(m_base + m0 + wr + i*16 + quad*4 + r);
        int col = n0 + wc + j*16 + lr;
        if constexpr (OUTBF) ((unsigned short*)C)[row*LDC + col] = f2bf(acc[i][j][r]);
        else                 ((float*)C)[row*LDC + col] = acc[i][j][r];
      }
}

// ------------------------------------- K1v: v32t[b][c][s] = bf16(x @ wv[used]^T)
__global__ __launch_bounds__(256) void k1_v32(const float* __restrict__ x,
    const float* __restrict__ wv, unsigned short* __restrict__ v32t) {
  int m0 = blockIdx.x * 64;
  __shared__ float Xs[64][36];
  __shared__ float Ws[32][36];
  int t = threadIdx.x;
  int m = t >> 2, c0 = (t & 3) * 8;
  float acc[8] = {};
  for (int k0 = 0; k0 < 512; k0 += 32) {
    #pragma unroll
    for (int u=0; u<2; u++){
      int idx = t + u*256;
      int r = idx >> 3, c4 = (idx & 7) * 4;
      *(float4*)&Xs[r][c4] = *(const float4*)(x + (size_t)(m0+r)*512 + k0 + c4);
    }
    { int r = t >> 3, c4 = (t & 7) * 4;
      int wrow = (r>>2)*64 + (r&3);
      *(float4*)&Ws[r][c4] = *(const float4*)(wv + (size_t)wrow*512 + k0 + c4);
    }
    __syncthreads();
    #pragma unroll
    for (int kk=0; kk<32; kk++){
      float xv = Xs[m][kk];
      #pragma unroll
      for (int j=0;j<8;j++) acc[j] += xv * Ws[c0+j][kk];
    }
    __syncthreads();
  }
  int tok = m0 + m, bb = tok >> 11, s = tok & 2047;
  #pragma unroll
  for (int j=0;j<8;j++)
    v32t[((size_t)(bb*32 + c0 + j))*2048 + s] = f2bf(acc[j]);
}

// -------------------- K2: MFMA flash attention (S^T trick), BK=64, XCD-local batches
__global__ __launch_bounds__(256,1) void k2_attn(
    const unsigned short* __restrict__ qkb, const unsigned short* __restrict__ v32t,
    const float* __restrict__ cAB, unsigned short* __restrict__ q32b){
  __shared__ __align__(16) char sm[57856];
  char* Qc  = sm;            // 2 sub-blocks [64][32] bf16 swizzled (8 KB)
  char* Ks  = sm + 8192;     // 2 sub-blocks [256][32] bf16 swizzled (32 KB)
  char* Vts = sm + 40960;    // [32][256+8] bf16, 528B rows (16.5 KB)
  float* OtL = (float*)sm;           // merge overlay: [4][64][36] f32
  float* mL  = (float*)(sm + 36864); // [4][64]
  float* lL  = (float*)(sm + 37888); // [4][64]

  int t = threadIdx.x, w = t>>6, l = t&63;
  int lr = l & 15, quad = l >> 4;
  int lin = blockIdx.x;
  int b = lin & 7;                   // one batch per XCD: K/Q/V stay in that XCD's L2
  int m0 = (lin >> 3) * 64;
  size_t bT = (size_t)b*2048;
  const char* qbase = (const char*)qkb + (bT + m0)*2048;       // q cols 0-511 (pre-scaled)
  const char* vbase = (const char*)v32t + (size_t)b*32*4096;

  f32x4 Ot[2][4] = {};
  float mold[4] = {-1e30f,-1e30f,-1e30f,-1e30f};
  float lsum[4] = {0.f,0.f,0.f,0.f};

  for (int step = 0; step < 8; ++step){
    int s0 = step*256;
    const char* kbase = (const char*)qkb + (bT + s0)*2048 + 1024; // k cols 512-1023
    __syncthreads();
    { // stage V^T tile [32 vcols][256 scols]
      int j = t>>3, seg = t&7;
      const uint4* vs = (const uint4*)(vbase + (size_t)j*4096 + (s0 + seg*32)*2);
      uint4* vd = (uint4*)(Vts + j*528 + seg*64);
      vd[0]=vs[0]; vd[1]=vs[1]; vd[2]=vs[2]; vd[3]=vs[3];
    }
    f32x4 acc[4][4] = {};   // S^T tile: acc[si][qj], sc=w*64+si*16+quad*4+r, qr=qj*16+lr
    for (int ec = 0; ec < 8; ++ec){  // BK=64: 8 iterations over the 512 K-dim
      __syncthreads();
      { int row = t>>2, sw = t&3, lc = sw ^ ((row>>1)&3);        // Q chunks [64][64]
        GLL16(qbase + (size_t)row*2048 + ec*128 +      lc*16, Qc +        w*1024);
        GLL16(qbase + (size_t)row*2048 + ec*128 + 64 + lc*16, Qc + 4096 + w*1024);
      }
      #pragma unroll
      for (int rd = 0; rd < 4; ++rd){                            // K chunks [256][64]
        int ch = rd*256 + t, row = ch>>2, sw = ch&3, lc = sw ^ ((row>>1)&3);
        GLL16(kbase + (size_t)row*2048 + ec*128 +      lc*16, Ks +         rd*4096 + w*1024);
        GLL16(kbase + (size_t)row*2048 + ec*128 + 64 + lc*16, Ks + 16384 + rd*4096 + w*1024);
      }
      __syncthreads();
      #pragma unroll
      for (int kk = 0; kk < 2; ++kk){
        bf16x8 af[4], bq[4];
        #pragma unroll
        for (int si = 0; si < 4; ++si){
          int row = w*64 + si*16 + lr;
          af[si] = *(const bf16x8*)(Ks + kk*16384 + row*64 + (quad ^ ((row>>1)&3))*16);
        }
        #pragma unroll
        for (int qj = 0; qj < 4; ++qj){
          int row = qj*16 + lr;
          bq[qj] = *(const bf16x8*)(Qc + kk*4096 + row*64 + (quad ^ ((row>>1)&3))*16);
        }
        #pragma unroll
        for (int si = 0; si < 4; ++si)
          #pragma unroll
          for (int qj = 0; qj < 4; ++qj)   // S^T = K * Q^T
            acc[si][qj] = __builtin_amdgcn_mfma_f32_16x16x32_bf16(af[si], bq[qj], acc[si][qj], 0,0,0);
      }
    }
    // online softmax over sc (rows of S^T) + PV from registers
    bf16x4 aV[2][4];
    #pragma unroll
    for (int vt=0; vt<2; ++vt)
      #pragma unroll
      for (int si=0; si<4; ++si)
        aV[vt][si] = *(const bf16x4*)(Vts + (vt*16+lr)*528 + (w*64 + si*16 + quad*4)*2);
    #pragma unroll
    for (int qj=0; qj<4; ++qj){
      float mt = -1e30f;
      #pragma unroll
      for (int si=0; si<4; ++si)
        #pragma unroll
        for (int r=0;r<4;++r) mt = fmaxf(mt, acc[si][qj][r]);
      mt = fmaxf(mt, __shfl_xor(mt, 16));
      mt = fmaxf(mt, __shfl_xor(mt, 32));
      float mn = fmaxf(mold[qj], mt);
      float al = __expf(mold[qj] - mn);
      mold[qj] = mn;
      float rs = 0.f;
      #pragma unroll
      for (int si=0; si<4; ++si)
        #pragma unroll
        for (int r=0;r<4;++r){
          float p = __expf(acc[si][qj][r] - mn);
          acc[si][qj][r] = p; rs += p;
        }
      rs += __shfl_xor(rs, 16); rs += __shfl_xor(rs, 32);
      lsum[qj] = lsum[qj]*al + rs;
      Ot[0][qj] *= al; Ot[1][qj] *= al;
      #pragma unroll
      for (int si=0; si<4; ++si){
        bf16x4 pb;                                  // P^T in exact B-operand layout
        pb[0]=(short)f2bf(acc[si][qj][0]); pb[1]=(short)f2bf(acc[si][qj][1]);
        pb[2]=(short)f2bf(acc[si][qj][2]); pb[3]=(short)f2bf(acc[si][qj][3]);
        Ot[0][qj] = __builtin_amdgcn_mfma_f32_16x16x16bf16_1k(aV[0][si], pb, Ot[0][qj], 0,0,0);
        Ot[1][qj] = __builtin_amdgcn_mfma_f32_16x16x16bf16_1k(aV[1][si], pb, Ot[1][qj], 0,0,0);
      }
    }
  }
  // merge 4 per-wave partial streams
  __syncthreads();
  #pragma unroll
  for (int qj=0; qj<4; ++qj){
    if (quad == 0){ mL[w*64 + qj*16 + lr] = mold[qj]; lL[w*64 + qj*16 + lr] = lsum[qj]; }
    *(f32x4*)(OtL + (size_t)(w*64 + qj*16 + lr)*36 + quad*4)      = Ot[0][qj];
    *(f32x4*)(OtL + (size_t)(w*64 + qj*16 + lr)*36 + 16 + quad*4) = Ot[1][qj];
  }
  __syncthreads();
  {
    int qr = t>>2, vg = (t&3)*8;
    float M = -1e30f;
    #pragma unroll
    for (int w4=0; w4<4; ++w4) M = fmaxf(M, mL[w4*64+qr]);
    float L = 0.f; float o[8] = {};
    #pragma unroll
    for (int w4=0; w4<4; ++w4){
      float a = __expf(mL[w4*64+qr] - M);
      L += a * lL[w4*64+qr];
      const float* Op = OtL + (size_t)(w4*64+qr)*36 + vg;
      #pragma unroll
      for (int j=0;j<8;++j) o[j] += a*Op[j];
    }
    float inv = 1.f/L;
    union { unsigned short h[8]; uint4 u; } res;
    #pragma unroll
    for (int j=0;j<8;++j){
      int cc = vg+j;
      float ov = o[j]*inv;
      res.h[j] = f2bf(cosf(ov)*cAB[cc] - sinf(ov)*cAB[32+cc]);
    }
    *(uint4*)(q32b + ((size_t)bT + m0 + qr)*32 + vg) = res.u;
  }
}

// ---- K3 (MFMA): x1 = LN(x + q32b@wo32b^T, g1,b1); fbuf = trig(x1[:, :8])
__global__ __launch_bounds__(256) void k3_proj_ln(const float* __restrict__ x,
    const unsigned short* __restrict__ q32b, const unsigned short* __restrict__ wo32b,
    const float* __restrict__ g1, const float* __restrict__ b1,
    const float* __restrict__ cAB, float* __restrict__ x1, float* __restrict__ fbuf) {
  __shared__ __align__(16) char sm3[36224];
  char* Ws = sm3;                          // [512][32] bf16 swizzled, 32 KB
  char* Qs = sm3 + 32768;                  // [32][32] bf16 swizzled, 2 KB
  float* red1 = (float*)(sm3 + 34816);     // [4][32]
  float* red2 = (float*)(sm3 + 35328);     // [4][32]
  float* mm   = (float*)(sm3 + 35840);     // [32]
  float* rr   = (float*)(sm3 + 35968);     // [32]
  int t = threadIdx.x, w = t>>6, l = t&63, lr = l&15, quad = l>>4;
  int tok0 = blockIdx.x * 32;
  #pragma unroll
  for (int i=0;i<8;++i){                   // stage wo32b: 2048 uint4
    int g = t + i*256, row = g>>2, ch = g&3;
    uint4 v = ((const uint4*)wo32b)[g];
    *(uint4*)(Ws + row*64 + (ch ^ ((row>>1)&3))*16) = v;
  }
  if (t < 128){                            // stage q tile: 128 uint4
    int row = t>>2, ch = t&3;
    uint4 v = ((const uint4*)(q32b + (size_t)tok0*32))[t];
    *(uint4*)(Qs + row*64 + (ch ^ ((row>>1)&3))*16) = v;
  }
  __syncthreads();
  bf16x8 af[2], bf[8];
  #pragma unroll
  for (int i=0;i<2;++i){
    int m = i*16 + lr;
    af[i] = *(const bf16x8*)(Qs + m*64 + (quad ^ ((m>>1)&3))*16);
  }
  #pragma unroll
  for (int j=0;j<8;++j){
    int n = w*128 + j*16 + lr;
    bf[j] = *(const bf16x8*)(Ws + n*64 + (quad ^ ((n>>1)&3))*16);
  }
  f32x4 acc[2][8];
  #pragma unroll
  for (int i=0;i<2;++i)
    #pragma unroll
    for (int j=0;j<8;++j){
      f32x4 z = {0.f,0.f,0.f,0.f};
      acc[i][j] = __builtin_amdgcn_mfma_f32_16x16x32_bf16(af[i], bf[j], z, 0,0,0);
    }
  // residual add + row-sum accumulation
  float s1[2][4] = {}, s2[2][4] = {};
  #pragma unroll
  for (int i=0;i<2;++i)
    #pragma unroll
    for (int r=0;r<4;++r){
      int m = i*16 + quad*4 + r;
      const float* xrow = x + (size_t)(tok0+m)*512 + w*128 + lr;
      #pragma unroll
      for (int j=0;j<8;++j){
        float v = acc[i][j][r] + xrow[j*16];
        acc[i][j][r] = v;
        s1[i][r] += v; s2[i][r] += v*v;
      }
    }
  #pragma unroll
  for (int off=1; off<16; off<<=1){
    #pragma unroll
    for (int i=0;i<2;++i)
      #pragma unroll
      for (int r=0;r<4;++r){
        s1[i][r] += __shfl_xor(s1[i][r], off);
        s2[i][r] += __shfl_xor(s2[i][r], off);
      }
  }
  if (lr == 0){
    #pragma unroll
    for (int i=0;i<2;++i)
      #pragma unroll
      for (int r=0;r<4;++r){
        int m = i*16 + quad*4 + r;
        red1[w*32 + m] = s1[i][r];
        red2[w*32 + m] = s2[i][r];
      }
  }
  __syncthreads();
  if (t < 32){
    float a = red1[t] + red1[32+t] + red1[64+t] + red1[96+t];
    float bb = red2[t] + red2[32+t] + red2[64+t] + red2[96+t];
    float mean = a * (1.f/512.f);
    float var  = bb * (1.f/512.f) - mean*mean;
    mm[t] = mean; rr[t] = rsqrtf(var + 1e-5f);
  }
  __syncthreads();
  float g1v[8], b1v[8];
  #pragma unroll
  for (int j=0;j<8;++j){
    int n = w*128 + j*16 + lr;
    g1v[j] = g1[n]; b1v[j] = b1[n];
  }
  #pragma unroll
  for (int i=0;i<2;++i)
    #pragma unroll
    for (int r=0;r<4;++r){
      int m = i*16 + quad*4 + r;
      float mean = mm[m], rstd = rr[m];
      float* orow = x1 + (size_t)(tok0+m)*512 + w*128 + lr;
      #pragma unroll
      for (int j=0;j<8;++j){
        float nv = (acc[i][j][r]-mean)*rstd*g1v[j] + b1v[j];
        orow[j*16] = nv;
        if (w == 0 && j == 0 && lr < 8)
          fbuf[(size_t)(tok0+m)*8 + lr] = cosf(nv)*cAB[64+lr] - sinf(nv)*cAB[72+lr];
      }
    }
}

// -------------------- K4a: Hb = bf16(relu(f @ w1^T)) for an 8192-row half
__global__ void k4a(const float* __restrict__ fbuf, const float* __restrict__ w1,
                    unsigned short* __restrict__ Hb, int row0){
  int i = blockIdx.x*256 + threadIdx.x;       // 2097152 chunks of 8 cols
  int tok = i >> 8;
  int c8 = (i & 255) * 8;
  const float* f = fbuf + (size_t)(row0 + tok)*8;
  float fv[8];
  #pragma unroll
  for (int c=0;c<8;c++) fv[c] = f[c];
  union { unsigned short h[8]; uint4 u; } o;
  #pragma unroll
  for (int j=0;j<8;j++){
    const float* wr = w1 + (size_t)(c8+j)*8;
    float s = 0.f;
    #pragma unroll
    for (int c=0;c<8;c++) s += fv[c]*wr[c];
    o.h[j] = f2bf(fmaxf(s, 0.f));
  }
  ((uint4*)Hb)[(size_t)tok*256 + (i & 255)] = o.u;
}

// --------------------------------------------- K5: out = LN(x1 + out2, g2, b2)
__global__ __launch_bounds__(256) void k5_ln2(const float* __restrict__ x1,
    const float* __restrict__ g2, const float* __restrict__ b2,
    float* __restrict__ out) {
  int tok = blockIdx.x, t = threadIdx.x;
  __shared__ float rs1[4], rs2[4], mv[2];
  float vals[2], ssum=0.f, ssq=0.f;
  #pragma unroll
  for (int u=0;u<2;u++){
    int e = t + u*256;
    float s = x1[(size_t)tok*512 + e] + out[(size_t)tok*512 + e];
    vals[u]=s; ssum+=s; ssq+=s*s;
  }
  #pragma unroll
  for (int off=32; off>0; off>>=1){ ssum += __shfl_down(ssum,off); ssq += __shfl_down(ssq,off); }
  int wid = t >> 6;
  if ((t & 63) == 0){ rs1[wid]=ssum; rs2[wid]=ssq; }
  __syncthreads();
  if (t == 0){
    float a = rs1[0]+rs1[1]+rs1[2]+rs1[3];
    float b = rs2[0]+rs2[1]+rs2[2]+rs2[3];
    float mean = a * (1.f/512.f);
    float var  = b * (1.f/512.f) - mean*mean;
    mv[0]=mean; mv[1]=rsqrtf(var + 1e-5f);
  }
  __syncthreads();
  float mean=mv[0], rstd=mv[1];
  #pragma unroll
  for (int u=0;u<2;u++){
    int e = t + u*256;
    out[(size_t)tok*512 + e] = (vals[u]-mean)*rstd*g2[e] + b2[e];
  }
}

// ---------------------------------------------------------------- launch
extern "C" void kernel_launch(void* const* d_in, const int* in_sizes, int n_in,
                              void* d_out, int out_size, void* d_ws, size_t ws_size,
                              hipStream_t stream) {
  const float* x  = (const float*)d_in[0];
  const float* wq = (const float*)d_in[1];
  const float* wk = (const float*)d_in[2];
  const float* wv = (const float*)d_in[3];
  const float* wo = (const float*)d_in[4];
  const float* hp = (const float*)d_in[5];
  const float* fp = (const float*)d_in[6];
  const float* w1 = (const float*)d_in[7];
  const float* w2 = (const float*)d_in[8];
  const float* g1 = (const float*)d_in[9];
  const float* b1 = (const float*)d_in[10];
  const float* g2 = (const float*)d_in[11];
  const float* b2 = (const float*)d_in[12];
  float* out = (float*)d_out;
  float* ws  = (float*)d_ws;

  // workspace layout (float slots), ~90.8 MB total:
  unsigned short* qkb  = (unsigned short*)(ws);             // [16384][1024] bf16 (33.5MB); reused as Hb half
  float*          x1   = ws + 8388608;                      // [16384][512] f32
  unsigned short* xb   = (unsigned short*)(ws + 16777216);  // [16384][512] bf16
  unsigned short* wqkb = (unsigned short*)(ws + 20971520);  // [1024][512] bf16 (wq scaled ; wk)
  unsigned short* w2b  = (unsigned short*)(ws + 21233664);  // [512][2048] bf16
  unsigned short* v32t = (unsigned short*)(ws + 21757952);  // [8][32][2048] bf16
  unsigned short* q32b = (unsigned short*)(ws + 22020096);  // [16384][32] bf16
  float*          fbuf = ws + 22544384;                     // [16384][8] f32
  unsigned short* wo32b= (unsigned short*)(ws + 22675456);  // [512][32] bf16
  float*          cAB  = ws + 22691840;                     // 80 consts
  unsigned short* Hb   = (unsigned short*)(ws);             // overlay (qkb dead after k2)

  k0_setup<<<17, 256, 0, stream>>>(hp, fp, wo, cAB, wo32b);
  kc_cast<<<4864, 256, 0, stream>>>(x, wq, wk, w2, xb, wqkb, w2b);
  gemm_bt<512,1024,true,8,128><<<1024, 256, 0, stream>>>(xb, wqkb, qkb, 0);
  k1_v32<<<256, 256, 0, stream>>>(x, wv, v32t);
  k2_attn<<<256, 256, 0, stream>>>(qkb, v32t, cAB, q32b);
  k3_proj_ln<<<512, 256, 0, stream>>>(x, q32b, wo32b, g1, b1, cAB, x1, fbuf);
  k4a<<<8192, 256, 0, stream>>>(fbuf, w1, Hb, 0);
  gemm_bt<2048,512,false,4,64><<<256, 256, 0, stream>>>(Hb, w2b, out, 0);
  k4a<<<8192, 256, 0, stream>>>(fbuf, w1, Hb, 8192);
  gemm_bt<2048,512,false,4,64><<<256, 256, 0, stream>>>(Hb, w2b, out, 8192);
  k5_ln2<<<16384, 256, 0, stream>>>(x1, g2, b2, out);
}

// Round 7
// 529.436 us; speedup vs baseline: 9.7704x; 1.0558x over previous
//
#include <hip/hip_runtime.h>
#include <hip/hip_bf16.h>
#include <math.h>

// B=8 T=2048 E=512 H=8 | NQ_H=4 NL=2 | NQ_F=8 FFN=2048
// Quantum circuits collapse to: qout_q = cos(x_q)*A_q - sin(x_q)*B_q (per-head/FFN consts).
// Round 7: k2 was latency-bound at 1 block/CU (grid 256, MfmaUtil 15.7%, VALU 21.5%,
// HBM 2.4% — nothing saturated; 64 barrier-drains/block fully exposed). KV-split x2:
// 512 blocks (2/CU co-resident, LDS 113KB/CU of 160), each does half the KV range and
// writes unnormalized (M,L,O) partials; new k2_merge kernel combines + trig epilogue.
// XCD batch mapping preserved (b = lin&7, 256-stride). All other kernels unchanged.

#define B_   8
#define T_   2048
#define E_   512

typedef __attribute__((ext_vector_type(8))) short bf16x8;
typedef __attribute__((ext_vector_type(4))) short bf16x4;
typedef __attribute__((ext_vector_type(4))) float f32x4;

#define GLL16(g, l) __builtin_amdgcn_global_load_lds((const __attribute__((address_space(1))) void*)(g), (__attribute__((address_space(3))) void*)(l), 16, 0, 0)

__device__ inline unsigned short f2bf(float f){
  union { float f; unsigned u; } v; v.f = f;
  unsigned r = v.u + 0x7fff + ((v.u >> 16) & 1);   // RTNE
  return (unsigned short)(r >> 16);
}

// ------------------------------------------- K0 (parallel): circuits + wo32b pack
__global__ __launch_bounds__(256) void k0_setup(const float* __restrict__ hp,
                         const float* __restrict__ fp,
                         const float* __restrict__ wo, float* __restrict__ cAB,
                         unsigned short* __restrict__ wo32b) {
  int t = threadIdx.x, bi = blockIdx.x;
  if (bi > 0) {                      // blocks 1..16: pack wo32b bf16 (coalesced)
    int gid = (bi-1)*256 + t;        // 4096 = 512 rows x 8 groups of 4 cols
    int e = gid >> 3, c4 = gid & 7;  // wo cols c4*64 .. c4*64+3 are contiguous
    float4 v = *(const float4*)(wo + (size_t)e*512 + c4*64);
    unsigned short h[4] = { f2bf(v.x), f2bf(v.y), f2bf(v.z), f2bf(v.w) };
    *(unsigned long long*)(wo32b + (size_t)e*32 + c4*4) = *(unsigned long long*)h;
    return;
  }
  // ---- block 0: FFN 8-qubit circuit, one amplitude per thread ----
  __shared__ float fst[256], tmp[256], ra[256], rb[256];
  fst[t] = (t == 0) ? 1.f : 0.f;
  __syncthreads();
  #pragma unroll
  for (int q = 0; q < 8; ++q) {      // RY layer (params row 0)
    int str = 1 << (7-q);
    float th = 0.5f * fp[q];
    float c = cosf(th), s = sinf(th);
    float self = fst[t], part = fst[t ^ str];
    float nv = (t & str) ? (c*self + s*part) : (c*self - s*part);
    __syncthreads();
    tmp[t] = nv;
    __syncthreads();
    fst[t] = tmp[t];
    __syncthreads();
  }
  #pragma unroll
  for (int g = 0; g < 8; ++g) {      // CNOT chain + ring
    int ctrl = (g < 7) ? g : 7, tgt = (g < 7) ? g+1 : 0;
    int cs = 1 << (7-ctrl), tsr = 1 << (7-tgt);
    float nv = fst[(t & cs) ? (t ^ tsr) : t];
    __syncthreads();
    fst[t] = nv;
    __syncthreads();
  }
  #pragma unroll
  for (int q = 0; q < 8; ++q) {      // <Z_q>, <X_q>
    int str = 1 << (7-q);
    float a = fst[t]*fst[t] * ((t & str) ? -1.f : 1.f);
    float b = fst[t]*fst[t ^ str];
    ra[t] = a; rb[t] = b;
    __syncthreads();
    for (int off = 128; off > 0; off >>= 1){
      if (t < off){ ra[t] += ra[t+off]; rb[t] += rb[t+off]; }
      __syncthreads();
    }
    if (t == 0){ cAB[64+q] = ra[0]; cAB[72+q] = rb[0]; }
    __syncthreads();
  }
  // ---- per-head 4-qubit circuits: 8 parallel threads, 16 amps in registers ----
  if (t < 8) {
    float st[16];
    #pragma unroll
    for (int i=0;i<16;i++) st[i]=0.f;
    st[0]=1.f;
    for (int l=0;l<2;l++){
      for (int q=0;q<4;q++){
        float th = 0.5f*hp[t*8 + l*4 + q];
        float c = cosf(th), s = sinf(th);
        int str = 1<<(3-q);
        for (int i=0;i<16;i++) if (!(i & str)) {
          float s0=st[i], s1=st[i|str];
          st[i]     = c*s0 - s*s1;
          st[i|str] = s*s0 + c*s1;
        }
      }
      for (int q=0;q<4;q++){
        int ctrl = (q<3)? q : 3, tgt = (q<3)? q+1 : 0;
        int cs = 1<<(3-ctrl), tsr = 1<<(3-tgt);
        for (int i=0;i<16;i++) if ((i&cs) && !(i&tsr)) {
          float tt = st[i]; st[i]=st[i|tsr]; st[i|tsr]=tt;
        }
      }
    }
    for (int q=0;q<4;q++){
      int str = 1<<(3-q);
      float A=0.f, Bv=0.f;
      for (int i=0;i<16;i++){
        A  += st[i]*st[i] * ((i&str)? -1.f : 1.f);
        Bv += st[i]*st[i^str];
      }
      cAB[t*4+q]    = A;
      cAB[32+t*4+q] = Bv;
    }
  }
}

// -------------------------------------- merged casts to bf16 (xb | wqkb,w2b)
__global__ __launch_bounds__(256) void kc_cast(const float* __restrict__ x,
                     const float* __restrict__ wq, const float* __restrict__ wk,
                     const float* __restrict__ w2, unsigned short* __restrict__ xb,
                     unsigned short* __restrict__ wqkb, unsigned short* __restrict__ w2b){
  int bi = blockIdx.x;
  if (bi < 4096) {                                 // x -> xb: 1048576 chunks of 8
    int i = bi*256 + threadIdx.x;
    const float4* p = (const float4*)x + (size_t)i*2;
    float4 a = p[0], b = p[1];
    union { unsigned short h[8]; uint4 u; } o;
    o.h[0]=f2bf(a.x); o.h[1]=f2bf(a.y); o.h[2]=f2bf(a.z); o.h[3]=f2bf(a.w);
    o.h[4]=f2bf(b.x); o.h[5]=f2bf(b.y); o.h[6]=f2bf(b.z); o.h[7]=f2bf(b.w);
    ((uint4*)xb)[i] = o.u;
    return;
  }
  int i = (bi-4096)*256 + threadIdx.x;             // 196608 chunks of 8
  const float* src; unsigned short* dst; float s = 1.f;
  if (i < 65536){
    int row = i >> 6, c8 = (i & 63)*8;
    if (row < 512){ src = wq + (size_t)row*512 + c8; s = 0.044194173824159216f; } // fold 1/sqrt(E)
    else          { src = wk + (size_t)(row-512)*512 + c8; }
    dst = wqkb + (size_t)row*512 + c8;
  } else {
    int j = i - 65536;
    src = w2 + (size_t)j*8; dst = w2b + (size_t)j*8;
  }
  float4 a = *(const float4*)src, b = *(const float4*)(src+4);
  union { unsigned short h[8]; uint4 u; } o;
  o.h[0]=f2bf(a.x*s); o.h[1]=f2bf(a.y*s); o.h[2]=f2bf(a.z*s); o.h[3]=f2bf(a.w*s);
  o.h[4]=f2bf(b.x*s); o.h[5]=f2bf(b.y*s); o.h[6]=f2bf(b.z*s); o.h[7]=f2bf(b.w*s);
  *(uint4*)dst = o.u;
}

// ------------- m97-style MFMA GEMM: C = A (MxK) * Bw^T (NxK), XCD-aware swizzle
// 1-D grid of GX*GM blocks; same-XCD blocks (lin%8) share A m-tiles via L2.
template<int K, int LDC, bool OUTBF, int GX, int GM>
__global__ __launch_bounds__(256,2) void gemm_bt(
    const unsigned short* __restrict__ A, const unsigned short* __restrict__ Bw,
    void* __restrict__ C, int m_base){
  __shared__ __align__(16) char sm[16384];
  char* As = sm; char* Bs = sm + 8192;             // [128][32] bf16, 64B rows, xor-swizzled
  int t = threadIdx.x, w = t>>6, l = t&63;
  int lr = l&15, quad = l>>4;
  int lin = blockIdx.x;
  int n0 = ((lin >> 3) % GX) * 128;
  int m0 = ((lin & 7) * (GM/8) + lin / (8*GX)) * 128;
  int wr = (w>>1)*64, wc = (w&1)*64;
  f32x4 acc[4][4] = {};
  for (int k0 = 0; k0 < K; k0 += 32){
    __syncthreads();
    #pragma unroll
    for (int c = 0; c < 2; ++c){
      int ch = c*256 + t, row = ch>>2, sw = ch&3, lc = sw ^ ((row>>1)&3);
      GLL16(A  + (size_t)(m0+row)*K + k0 + lc*8, As + c*4096 + w*1024);
      GLL16(Bw + (size_t)(n0+row)*K + k0 + lc*8, Bs + c*4096 + w*1024);
    }
    __syncthreads();
    bf16x8 af[4], bg[4];
    #pragma unroll
    for (int i=0;i<4;++i){
      int ra = wr + i*16 + lr;
      af[i] = *(const bf16x8*)(As + ra*64 + (quad ^ ((ra>>1)&3))*16);
      int rb = wc + i*16 + lr;
      bg[i] = *(const bf16x8*)(Bs + rb*64 + (quad ^ ((rb>>1)&3))*16);
    }
    #pragma unroll
    for (int i=0;i<4;++i)
      #pragma unroll
      for (int j=0;j<4;++j)
        acc[i][j] = __builtin_amdgcn_mfma_f32_16x16x32_bf16(af[i], bg[j], acc[i][j], 0,0,0);
  }
  #pragma unroll
  for (int i=0;i<4;++i)
    #pragma unroll
    for (int j=0;j<4;++j)
      #pragma unroll
      for (int r=0;r<4;++r){
        size_t row = (size_t)(m_base + m0 + wr + i*16 + quad*4 + r);
        int col = n0 + wc + j*16 + lr;
        if constexpr (OUTBF) ((unsigned short*)C)[row*LDC + col] = f2bf(acc[i][j][r]);
        else                 ((float*)C)[row*LDC + col] = acc[i][j][r];
      }
}

// ------------------------------------- K1v: v32t[b][c][s] = bf16(x @ wv[used]^T)
__global__ __launch_bounds__(256) void k1_v32(const float* __restrict__ x,
    const float* __restrict__ wv, unsigned short* __restrict__ v32t) {
  int m0 = blockIdx.x * 64;
  __shared__ float Xs[64][36];
  __shared__ float Ws[32][36];
  int t = threadIdx.x;
  int m = t >> 2, c0 = (t & 3) * 8;
  float acc[8] = {};
  for (int k0 = 0; k0 < 512; k0 += 32) {
    #pragma unroll
    for (int u=0; u<2; u++){
      int idx = t + u*256;
      int r = idx >> 3, c4 = (idx & 7) * 4;
      *(float4*)&Xs[r][c4] = *(const float4*)(x + (size_t)(m0+r)*512 + k0 + c4);
    }
    { int r = t >> 3, c4 = (t & 7) * 4;
      int wrow = (r>>2)*64 + (r&3);
      *(float4*)&Ws[r][c4] = *(const float4*)(wv + (size_t)wrow*512 + k0 + c4);
    }
    __syncthreads();
    #pragma unroll
    for (int kk=0; kk<32; kk++){
      float xv = Xs[m][kk];
      #pragma unroll
      for (int j=0;j<8;j++) acc[j] += xv * Ws[c0+j][kk];
    }
    __syncthreads();
  }
  int tok = m0 + m, bb = tok >> 11, s = tok & 2047;
  #pragma unroll
  for (int j=0;j<8;j++)
    v32t[((size_t)(bb*32 + c0 + j))*2048 + s] = f2bf(acc[j]);
}

// ------ K2: MFMA flash attention (S^T trick), BK=64, XCD-local, KV-split x2
__global__ __launch_bounds__(256,1) void k2_attn(
    const unsigned short* __restrict__ qkb, const unsigned short* __restrict__ v32t,
    float* __restrict__ Opart, float* __restrict__ mlb){
  __shared__ __align__(16) char sm[57856];
  char* Qc  = sm;            // 2 sub-blocks [64][32] bf16 swizzled (8 KB)
  char* Ks  = sm + 8192;     // 2 sub-blocks [256][32] bf16 swizzled (32 KB)
  char* Vts = sm + 40960;    // [32][256+8] bf16, 528B rows (16.5 KB)
  float* OtL = (float*)sm;           // merge overlay: [4][64][36] f32
  float* mL  = (float*)(sm + 36864); // [4][64]
  float* lL  = (float*)(sm + 37888); // [4][64]

  int t = threadIdx.x, w = t>>6, l = t&63;
  int lr = l & 15, quad = l >> 4;
  int lin = blockIdx.x;
  int b = lin & 7;                   // one batch per XCD (stride-256 preserves this)
  int m0 = ((lin >> 3) & 31) * 64;
  int half = lin >> 8;               // KV half: s in [half*1024, half*1024+1024)
  size_t bT = (size_t)b*2048;
  const char* qbase = (const char*)qkb + (bT + m0)*2048;       // q cols 0-511 (pre-scaled)
  const char* vbase = (const char*)v32t + (size_t)b*32*4096;

  f32x4 Ot[2][4] = {};
  float mold[4] = {-1e30f,-1e30f,-1e30f,-1e30f};
  float lsum[4] = {0.f,0.f,0.f,0.f};

  for (int step = half*4; step < half*4 + 4; ++step){
    int s0 = step*256;
    const char* kbase = (const char*)qkb + (bT + s0)*2048 + 1024; // k cols 512-1023
    __syncthreads();
    { // stage V^T tile [32 vcols][256 scols]
      int j = t>>3, seg = t&7;
      const uint4* vs = (const uint4*)(vbase + (size_t)j*4096 + (s0 + seg*32)*2);
      uint4* vd = (uint4*)(Vts + j*528 + seg*64);
      vd[0]=vs[0]; vd[1]=vs[1]; vd[2]=vs[2]; vd[3]=vs[3];
    }
    f32x4 acc[4][4] = {};   // S^T tile: acc[si][qj], sc=w*64+si*16+quad*4+r, qr=qj*16+lr
    for (int ec = 0; ec < 8; ++ec){  // BK=64: 8 iterations over the 512 K-dim
      __syncthreads();
      { int row = t>>2, sw = t&3, lc = sw ^ ((row>>1)&3);        // Q chunks [64][64]
        GLL16(qbase + (size_t)row*2048 + ec*128 +      lc*16, Qc +        w*1024);
        GLL16(qbase + (size_t)row*2048 + ec*128 + 64 + lc*16, Qc + 4096 + w*1024);
      }
      #pragma unroll
      for (int rd = 0; rd < 4; ++rd){                            // K chunks [256][64]
        int ch = rd*256 + t, row = ch>>2, sw = ch&3, lc = sw ^ ((row>>1)&3);
        GLL16(kbase + (size_t)row*2048 + ec*128 +      lc*16, Ks +         rd*4096 + w*1024);
        GLL16(kbase + (size_t)row*2048 + ec*128 + 64 + lc*16, Ks + 16384 + rd*4096 + w*1024);
      }
      __syncthreads();
      #pragma unroll
      for (int kk = 0; kk < 2; ++kk){
        bf16x8 af[4], bq[4];
        #pragma unroll
        for (int si = 0; si < 4; ++si){
          int row = w*64 + si*16 + lr;
          af[si] = *(const bf16x8*)(Ks + kk*16384 + row*64 + (quad ^ ((row>>1)&3))*16);
        }
        #pragma unroll
        for (int qj = 0; qj < 4; ++qj){
          int row = qj*16 + lr;
          bq[qj] = *(const bf16x8*)(Qc + kk*4096 + row*64 + (quad ^ ((row>>1)&3))*16);
        }
        #pragma unroll
        for (int si = 0; si < 4; ++si)
          #pragma unroll
          for (int qj = 0; qj < 4; ++qj)   // S^T = K * Q^T
            acc[si][qj] = __builtin_amdgcn_mfma_f32_16x16x32_bf16(af[si], bq[qj], acc[si][qj], 0,0,0);
      }
    }
    // online softmax over sc (rows of S^T) + PV from registers
    bf16x4 aV[2][4];
    #pragma unroll
    for (int vt=0; vt<2; ++vt)
      #pragma unroll
      for (int si=0; si<4; ++si)
        aV[vt][si] = *(const bf16x4*)(Vts + (vt*16+lr)*528 + (w*64 + si*16 + quad*4)*2);
    #pragma unroll
    for (int qj=0; qj<4; ++qj){
      float mt = -1e30f;
      #pragma unroll
      for (int si=0; si<4; ++si)
        #pragma unroll
        for (int r=0;r<4;++r) mt = fmaxf(mt, acc[si][qj][r]);
      mt = fmaxf(mt, __shfl_xor(mt, 16));
      mt = fmaxf(mt, __shfl_xor(mt, 32));
      float mn = fmaxf(mold[qj], mt);
      float al = __expf(mold[qj] - mn);
      mold[qj] = mn;
      float rs = 0.f;
      #pragma unroll
      for (int si=0; si<4; ++si)
        #pragma unroll
        for (int r=0;r<4;++r){
          float p = __expf(acc[si][qj][r] - mn);
          acc[si][qj][r] = p; rs += p;
        }
      rs += __shfl_xor(rs, 16); rs += __shfl_xor(rs, 32);
      lsum[qj] = lsum[qj]*al + rs;
      Ot[0][qj] *= al; Ot[1][qj] *= al;
      #pragma unroll
      for (int si=0; si<4; ++si){
        bf16x4 pb;                                  // P^T in exact B-operand layout
        pb[0]=(short)f2bf(acc[si][qj][0]); pb[1]=(short)f2bf(acc[si][qj][1]);
        pb[2]=(short)f2bf(acc[si][qj][2]); pb[3]=(short)f2bf(acc[si][qj][3]);
        Ot[0][qj] = __builtin_amdgcn_mfma_f32_16x16x16bf16_1k(aV[0][si], pb, Ot[0][qj], 0,0,0);
        Ot[1][qj] = __builtin_amdgcn_mfma_f32_16x16x16bf16_1k(aV[1][si], pb, Ot[1][qj], 0,0,0);
      }
    }
  }
  // merge 4 per-wave partial streams -> unnormalized half-partials to global
  __syncthreads();
  #pragma unroll
  for (int qj=0; qj<4; ++qj){
    if (quad == 0){ mL[w*64 + qj*16 + lr] = mold[qj]; lL[w*64 + qj*16 + lr] = lsum[qj]; }
    *(f32x4*)(OtL + (size_t)(w*64 + qj*16 + lr)*36 + quad*4)      = Ot[0][qj];
    *(f32x4*)(OtL + (size_t)(w*64 + qj*16 + lr)*36 + 16 + quad*4) = Ot[1][qj];
  }
  __syncthreads();
  {
    int qr = t>>2, vg = (t&3)*8;
    float M = -1e30f;
    #pragma unroll
    for (int w4=0; w4<4; ++w4) M = fmaxf(M, mL[w4*64+qr]);
    float L = 0.f; float o[8] = {};
    #pragma unroll
    for (int w4=0; w4<4; ++w4){
      float a = __expf(mL[w4*64+qr] - M);
      L += a * lL[w4*64+qr];
      const float* Op = OtL + (size_t)(w4*64+qr)*36 + vg;
      #pragma unroll
      for (int j=0;j<8;++j) o[j] += a*Op[j];
    }
    size_t tok = bT + m0 + qr;
    float* od = Opart + ((size_t)half*16384 + tok)*32 + vg;
    *(float4*)od     = make_float4(o[0],o[1],o[2],o[3]);
    *(float4*)(od+4) = make_float4(o[4],o[5],o[6],o[7]);
    if ((t&3) == 0){
      mlb[((size_t)half*16384 + tok)*2]     = M;
      mlb[((size_t)half*16384 + tok)*2 + 1] = L;
    }
  }
}

// ---------- K2m: combine the two KV halves + circuit trig -> q32b (bf16)
__global__ __launch_bounds__(256) void k2_merge(const float* __restrict__ Opart,
    const float* __restrict__ mlb, const float* __restrict__ cAB,
    unsigned short* __restrict__ q32b){
  int g = blockIdx.x*256 + threadIdx.x;     // 65536 = 16384 tokens x 4 col-groups
  int tok = g >> 2, vg = (g & 3) * 8;
  float m0v = mlb[(size_t)tok*2],           l0 = mlb[(size_t)tok*2 + 1];
  float m1v = mlb[(size_t)(16384+tok)*2],   l1 = mlb[(size_t)(16384+tok)*2 + 1];
  float M = fmaxf(m0v, m1v);
  float a0 = __expf(m0v - M), a1 = __expf(m1v - M);
  float inv = 1.f / (a0*l0 + a1*l1);
  const float* O0 = Opart + (size_t)tok*32 + vg;
  const float* O1 = Opart + (size_t)(16384+tok)*32 + vg;
  union { unsigned short h[8]; uint4 u; } res;
  #pragma unroll
  for (int j=0;j<8;++j){
    float ov = (a0*O0[j] + a1*O1[j]) * inv;
    int cc = vg + j;
    res.h[j] = f2bf(cosf(ov)*cAB[cc] - sinf(ov)*cAB[32+cc]);
  }
  *(uint4*)(q32b + (size_t)tok*32 + vg) = res.u;
}

// ---- K3 (MFMA): x1 = LN(x + q32b@wo32b^T, g1,b1); fbuf = trig(x1[:, :8])
__global__ __launch_bounds__(256) void k3_proj_ln(const float* __restrict__ x,
    const unsigned short* __restrict__ q32b, const unsigned short* __restrict__ wo32b,
    const float* __restrict__ g1, const float* __restrict__ b1,
    const float* __restrict__ cAB, float* __restrict__ x1, float* __restrict__ fbuf) {
  __shared__ __align__(16) char sm3[36224];
  char* Ws = sm3;                          // [512][32] bf16 swizzled, 32 KB
  char* Qs = sm3 + 32768;                  // [32][32] bf16 swizzled, 2 KB
  float* red1 = (float*)(sm3 + 34816);     // [4][32]
  float* red2 = (float*)(sm3 + 35328);     // [4][32]
  float* mm   = (float*)(sm3 + 35840);     // [32]
  float* rr   = (float*)(sm3 + 35968);     // [32]
  int t = threadIdx.x, w = t>>6, l = t&63, lr = l&15, quad = l>>4;
  int tok0 = blockIdx.x * 32;
  #pragma unroll
  for (int i=0;i<8;++i){                   // stage wo32b: 2048 uint4
    int g = t + i*256, row = g>>2, ch = g&3;
    uint4 v = ((const uint4*)wo32b)[g];
    *(uint4*)(Ws + row*64 + (ch ^ ((row>>1)&3))*16) = v;
  }
  if (t < 128){                            // stage q tile: 128 uint4
    int row = t>>2, ch = t&3;
    uint4 v = ((const uint4*)(q32b + (size_t)tok0*32))[t];
    *(uint4*)(Qs + row*64 + (ch ^ ((row>>1)&3))*16) = v;
  }
  __syncthreads();
  bf16x8 af[2], bf[8];
  #pragma unroll
  for (int i=0;i<2;++i){
    int m = i*16 + lr;
    af[i] = *(const bf16x8*)(Qs + m*64 + (quad ^ ((m>>1)&3))*16);
  }
  #pragma unroll
  for (int j=0;j<8;++j){
    int n = w*128 + j*16 + lr;
    bf[j] = *(const bf16x8*)(Ws + n*64 + (quad ^ ((n>>1)&3))*16);
  }
  f32x4 acc[2][8];
  #pragma unroll
  for (int i=0;i<2;++i)
    #pragma unroll
    for (int j=0;j<8;++j){
      f32x4 z = {0.f,0.f,0.f,0.f};
      acc[i][j] = __builtin_amdgcn_mfma_f32_16x16x32_bf16(af[i], bf[j], z, 0,0,0);
    }
  // residual add + row-sum accumulation
  float s1[2][4] = {}, s2[2][4] = {};
  #pragma unroll
  for (int i=0;i<2;++i)
    #pragma unroll
    for (int r=0;r<4;++r){
      int m = i*16 + quad*4 + r;
      const float* xrow = x + (size_t)(tok0+m)*512 + w*128 + lr;
      #pragma unroll
      for (int j=0;j<8;++j){
        float v = acc[i][j][r] + xrow[j*16];
        acc[i][j][r] = v;
        s1[i][r] += v; s2[i][r] += v*v;
      }
    }
  #pragma unroll
  for (int off=1; off<16; off<<=1){
    #pragma unroll
    for (int i=0;i<2;++i)
      #pragma unroll
      for (int r=0;r<4;++r){
        s1[i][r] += __shfl_xor(s1[i][r], off);
        s2[i][r] += __shfl_xor(s2[i][r], off);
      }
  }
  if (lr == 0){
    #pragma unroll
    for (int i=0;i<2;++i)
      #pragma unroll
      for (int r=0;r<4;++r){
        int m = i*16 + quad*4 + r;
        red1[w*32 + m] = s1[i][r];
        red2[w*32 + m] = s2[i][r];
      }
  }
  __syncthreads();
  if (t < 32){
    float a = red1[t] + red1[32+t] + red1[64+t] + red1[96+t];
    float bb = red2[t] + red2[32+t] + red2[64+t] + red2[96+t];
    float mean = a * (1.f/512.f);
    float var  = bb * (1.f/512.f) - mean*mean;
    mm[t] = mean; rr[t] = rsqrtf(var + 1e-5f);
  }
  __syncthreads();
  float g1v[8], b1v[8];
  #pragma unroll
  for (int j=0;j<8;++j){
    int n = w*128 + j*16 + lr;
    g1v[j] = g1[n]; b1v[j] = b1[n];
  }
  #pragma unroll
  for (int i=0;i<2;++i)
    #pragma unroll
    for (int r=0;r<4;++r){
      int m = i*16 + quad*4 + r;
      float mean = mm[m], rstd = rr[m];
      float* orow = x1 + (size_t)(tok0+m)*512 + w*128 + lr;
      #pragma unroll
      for (int j=0;j<8;++j){
        float nv = (acc[i][j][r]-mean)*rstd*g1v[j] + b1v[j];
        orow[j*16] = nv;
        if (w == 0 && j == 0 && lr < 8)
          fbuf[(size_t)(tok0+m)*8 + lr] = cosf(nv)*cAB[64+lr] - sinf(nv)*cAB[72+lr];
      }
    }
}

// -------------------- K4a: Hb = bf16(relu(f @ w1^T)) for an 8192-row half
__global__ void k4a(const float* __restrict__ fbuf, const float* __restrict__ w1,
                    unsigned short* __restrict__ Hb, int row0){
  int i = blockIdx.x*256 + threadIdx.x;       // 2097152 chunks of 8 cols
  int tok = i >> 8;
  int c8 = (i & 255) * 8;
  const float* f = fbuf + (size_t)(row0 + tok)*8;
  float fv[8];
  #pragma unroll
  for (int c=0;c<8;c++) fv[c] = f[c];
  union { unsigned short h[8]; uint4 u; } o;
  #pragma unroll
  for (int j=0;j<8;j++){
    const float* wr = w1 + (size_t)(c8+j)*8;
    float s = 0.f;
    #pragma unroll
    for (int c=0;c<8;c++) s += fv[c]*wr[c];
    o.h[j] = f2bf(fmaxf(s, 0.f));
  }
  ((uint4*)Hb)[(size_t)tok*256 + (i & 255)] = o.u;
}

// --------------------------------------------- K5: out = LN(x1 + out2, g2, b2)
__global__ __launch_bounds__(256) void k5_ln2(const float* __restrict__ x1,
    const float* __restrict__ g2, const float* __restrict__ b2,
    float* __restrict__ out) {
  int tok = blockIdx.x, t = threadIdx.x;
  __shared__ float rs1[4], rs2[4], mv[2];
  float vals[2], ssum=0.f, ssq=0.f;
  #pragma unroll
  for (int u=0;u<2;u++){
    int e = t + u*256;
    float s = x1[(size_t)tok*512 + e] + out[(size_t)tok*512 + e];
    vals[u]=s; ssum+=s; ssq+=s*s;
  }
  #pragma unroll
  for (int off=32; off>0; off>>=1){ ssum += __shfl_down(ssum,off); ssq += __shfl_down(ssq,off); }
  int wid = t >> 6;
  if ((t & 63) == 0){ rs1[wid]=ssum; rs2[wid]=ssq; }
  __syncthreads();
  if (t == 0){
    float a = rs1[0]+rs1[1]+rs1[2]+rs1[3];
    float b = rs2[0]+rs2[1]+rs2[2]+rs2[3];
    float mean = a * (1.f/512.f);
    float var  = b * (1.f/512.f) - mean*mean;
    mv[0]=mean; mv[1]=rsqrtf(var + 1e-5f);
  }
  __syncthreads();
  float mean=mv[0], rstd=mv[1];
  #pragma unroll
  for (int u=0;u<2;u++){
    int e = t + u*256;
    out[(size_t)tok*512 + e] = (vals[u]-mean)*rstd*g2[e] + b2[e];
  }
}

// ---------------------------------------------------------------- launch
extern "C" void kernel_launch(void* const* d_in, const int* in_sizes, int n_in,
                              void* d_out, int out_size, void* d_ws, size_t ws_size,
                              hipStream_t stream) {
  const float* x  = (const float*)d_in[0];
  const float* wq = (const float*)d_in[1];
  const float* wk = (const float*)d_in[2];
  const float* wv = (const float*)d_in[3];
  const float* wo = (const float*)d_in[4];
  const float* hp = (const float*)d_in[5];
  const float* fp = (const float*)d_in[6];
  const float* w1 = (const float*)d_in[7];
  const float* w2 = (const float*)d_in[8];
  const float* g1 = (const float*)d_in[9];
  const float* b1 = (const float*)d_in[10];
  const float* g2 = (const float*)d_in[11];
  const float* b2 = (const float*)d_in[12];
  float* out = (float*)d_out;
  float* ws  = (float*)d_ws;

  // workspace layout (float slots), ~95.2 MB total:
  unsigned short* qkb  = (unsigned short*)(ws);             // [16384][1024] bf16 (33.5MB); reused as Hb half
  float*          x1   = ws + 8388608;                      // [16384][512] f32
  unsigned short* xb   = (unsigned short*)(ws + 16777216);  // [16384][512] bf16
  unsigned short* wqkb = (unsigned short*)(ws + 20971520);  // [1024][512] bf16 (wq scaled ; wk)
  unsigned short* w2b  = (unsigned short*)(ws + 21233664);  // [512][2048] bf16
  unsigned short* v32t = (unsigned short*)(ws + 21757952);  // [8][32][2048] bf16
  unsigned short* q32b = (unsigned short*)(ws + 22020096);  // [16384][32] bf16
  float*          fbuf = ws + 22544384;                     // [16384][8] f32
  unsigned short* wo32b= (unsigned short*)(ws + 22675456);  // [512][32] bf16
  float*          cAB  = ws + 22691840;                     // 80 consts (pad to 128)
  float*          Opart= ws + 22691968;                     // [2][16384][32] f32 (4MB)
  float*          mlb  = ws + 23740544;                     // [2][16384][2] f32
  unsigned short* Hb   = (unsigned short*)(ws);             // overlay (qkb dead after k2)

  k0_setup<<<17, 256, 0, stream>>>(hp, fp, wo, cAB, wo32b);
  kc_cast<<<4864, 256, 0, stream>>>(x, wq, wk, w2, xb, wqkb, w2b);
  gemm_bt<512,1024,true,8,128><<<1024, 256, 0, stream>>>(xb, wqkb, qkb, 0);
  k1_v32<<<256, 256, 0, stream>>>(x, wv, v32t);
  k2_attn<<<512, 256, 0, stream>>>(qkb, v32t, Opart, mlb);
  k2_merge<<<256, 256, 0, stream>>>(Opart, mlb, cAB, q32b);
  k3_proj_ln<<<512, 256, 0, stream>>>(x, q32b, wo32b, g1, b1, cAB, x1, fbuf);
  k4a<<<8192, 256, 0, stream>>>(fbuf, w1, Hb, 0);
  gemm_bt<2048,512,false,4,64><<<256, 256, 0, stream>>>(Hb, w2b, out, 0);
  k4a<<<8192, 256, 0, stream>>>(fbuf, w1, Hb, 8192);
  gemm_bt<2048,512,false,4,64><<<256, 256, 0, stream>>>(Hb, w2b, out, 8192);
  k5_ln2<<<16384, 256, 0, stream>>>(x1, g2, b2, out);
}